// Round 18
// baseline (397.942 us; speedup 1.0000x reference)
//
#include <hip/hip_runtime.h>
#include <math.h>

#define GRID_N 512
#define IM_N   256
#define NCOIL  8
#define NK     131072
#define PLANE  (GRID_N*GRID_N)
#define JW     6
#define NBIN   (GRID_N*GRID_N/512*512)  /* 262144 (col,by) bins */
#define WSZ    11
#define NWIN   47                        /* ceil(512/11) */
#define ACCROWS 528
#define BETA_F 13.8551003f   /* pi*sqrt((6/2)^2*(2-0.5)^2 - 0.8) */
#define KSCALE 81.48733086305042f  /* 512/(2*pi) */

struct cplx { float x, y; };

__device__ __forceinline__ float bessel_i0f(float x){
  // Abramowitz & Stegun 9.8.1 / 9.8.2, rel err < 2e-7
  if (x < 3.75f){
    float t = x*(1.0f/3.75f); t = t*t;
    return 1.0f + t*(3.5156229f + t*(3.0899424f + t*(1.2067492f
           + t*(0.2659732f + t*(0.0360768f + t*0.0045813f)))));
  } else {
    float t = 3.75f/x;
    float p = 0.39894228f + t*(0.01328592f + t*(0.00225319f + t*(-0.00157565f
            + t*(0.00916281f + t*(-0.02057706f + t*(0.02635537f
            + t*(-0.01647633f + t*0.00392377f)))))));
    return p * __expf(x) * rsqrtf(x);
  }
}

__device__ __forceinline__ float kb_w(float u){   // 1-axis KB weight, |u|<=3
  float uu = u*(1.0f/3.0f);
  float q = fmaxf(1.0f - uu*uu, 0.0f);
  return bessel_i0f(BETA_F*sqrtf(q)) * (1.0f/6.0f);
}

__device__ __forceinline__ unsigned bf16_of(float f){
  unsigned u = __float_as_uint(f);
  return (u + 0x8000u) >> 16;
}
__device__ __forceinline__ float bf_lo(unsigned w){ return __uint_as_float(w << 16); }
__device__ __forceinline__ float bf_hi(unsigned w){ return __uint_as_float(w & 0xFFFF0000u); }

// Kaiser-Bessel apodization correction row table sc[256]
__global__ void k_sc_table(float* sc){
  int i = threadIdx.x;
  if (i >= IM_N) return;
  float n  = (i - IM_N*0.5f) * (1.0f/GRID_N);
  float pj = 3.14159265358979f * (float)JW * n;
  float t  = BETA_F*BETA_F - pj*pj;
  float sp = sqrtf(fmaxf(t, 1e-12f));
  float sn = sqrtf(fmaxf(-t, 1e-12f));
  float ft = (t > 0.0f) ? (sinhf(sp)/sp) : (sinf(sn)/sn);
  float sc0 = sinhf(BETA_F)/BETA_F;
  sc[i] = sc0/ft;
}

__global__ void k_zero1(float* p, int n){
  int i = blockIdx.x*blockDim.x + threadIdx.x;
  if (i < n) p[i] = 0.f;
}

// FUSED: pad + apodize + smap-multiply + fwd 512-pt FFT row (DIR=-1, scale 1)
// block = c*512+y; rows y>=256 are identically zero -> direct zero store.
__global__ void k_fft_fill(const float* __restrict__ ximg, const float* __restrict__ sr,
                           const float* __restrict__ si, const float* __restrict__ sc,
                           cplx* __restrict__ buf){
  __shared__ cplx lds[GRID_N];
  int blk = blockIdx.x;                        // c*512 + y
  int c = blk >> 9, y = blk & (GRID_N-1);
  cplx* p = buf + (size_t)blk * GRID_N;
  int tid = threadIdx.x;
  if (y >= IM_N){
    cplx z; z.x = 0.f; z.y = 0.f;
    for (int i = tid; i < GRID_N; i += 256) p[i] = z;
    return;
  }
  float scy = sc[y];
  for (int i = tid; i < GRID_N; i += 256){
    int r = __brev((unsigned)i) >> 23;
    cplx v; v.x = 0.f; v.y = 0.f;
    if (i < IM_N){
      float vv = ximg[(y<<8)|i] * scy * sc[i];
      int gi = (c << 16) | (y << 8) | i;
      v.x = vv * sr[gi]; v.y = vv * si[gi];
    }
    lds[r] = v;
  }
  __syncthreads();
  for (int half = 1; half < GRID_N; half <<= 1){
    int j = tid & (half-1);
    int k = ((tid & ~(half-1)) << 1) | j;
    float ang = -3.14159265358979f * (float)j / (float)half;
    float sw, cw; __sincosf(ang, &sw, &cw);
    cplx u = lds[k];
    cplx v = lds[k+half];
    cplx t; t.x = v.x*cw - v.y*sw; t.y = v.x*sw + v.y*cw;
    lds[k].x      = u.x + t.x; lds[k].y      = u.y + t.y;
    lds[k+half].x = u.x - t.x; lds[k+half].y = u.y - t.y;
    __syncthreads();
  }
  for (int i = tid; i < GRID_N; i += 256) p[i] = lds[i];
}

// in-place 512-pt radix-2 FFT on each contiguous row; DIR=-1 fwd, +1 inv(unnorm)
template<int DIR>
__global__ void k_fft_rows(cplx* __restrict__ buf, float scale){
  __shared__ cplx lds[GRID_N];
  cplx* p = buf + (size_t)blockIdx.x * GRID_N;
  int tid = threadIdx.x;                       // 256 threads
  for (int i = tid; i < GRID_N; i += 256){
    int r = __brev((unsigned)i) >> 23;         // 9-bit reverse
    lds[r] = p[i];
  }
  __syncthreads();
  for (int half = 1; half < GRID_N; half <<= 1){
    int j = tid & (half-1);
    int k = ((tid & ~(half-1)) << 1) | j;
    float ang = (float)DIR * 3.14159265358979f * (float)j / (float)half;
    float sw, cw; __sincosf(ang, &sw, &cw);
    cplx u = lds[k];
    cplx v = lds[k+half];
    cplx t; t.x = v.x*cw - v.y*sw; t.y = v.x*sw + v.y*cw;
    lds[k].x      = u.x + t.x; lds[k].y      = u.y + t.y;
    lds[k+half].x = u.x - t.x; lds[k+half].y = u.y - t.y;
    __syncthreads();
  }
  for (int i = tid; i < GRID_N; i += 256){
    cplx v = lds[i]; v.x *= scale; v.y *= scale; p[i] = v;
  }
}

// crop variant: 256 rows per coil (y<256), inverse FFT over x, write x<256 only
__global__ void k_fft_rows_c(cplx* __restrict__ buf, float scale){
  __shared__ cplx lds[GRID_N];
  int b = blockIdx.x;                          // c*256 + y
  int c = b >> 8, y = b & (IM_N-1);
  cplx* p = buf + (size_t)c*PLANE + (size_t)y*GRID_N;
  int tid = threadIdx.x;
  for (int i = tid; i < GRID_N; i += 256){
    int r = __brev((unsigned)i) >> 23;
    lds[r] = p[i];
  }
  __syncthreads();
  for (int half = 1; half < GRID_N; half <<= 1){
    int j = tid & (half-1);
    int k = ((tid & ~(half-1)) << 1) | j;
    float ang = 3.14159265358979f * (float)j / (float)half;
    float sw, cw; __sincosf(ang, &sw, &cw);
    cplx u = lds[k];
    cplx v = lds[k+half];
    cplx t; t.x = v.x*cw - v.y*sw; t.y = v.x*sw + v.y*cw;
    lds[k].x      = u.x + t.x; lds[k].y      = u.y + t.y;
    lds[k+half].x = u.x - t.x; lds[k+half].y = u.y - t.y;
    __syncthreads();
  }
  for (int i = tid; i < IM_N; i += 256){       // crop: only x<256 consumed
    cplx v = lds[i]; v.x *= scale; v.y *= scale; p[i] = v;
  }
}

// 512x512 (or partial) tile transpose per coil plane, out[X][Y] = in[Y][X]
__global__ void k_transpose(const cplx* __restrict__ in, cplx* __restrict__ out){
  __shared__ cplx tile[32][33];
  int c  = blockIdx.z;
  int x0 = blockIdx.x*32, y0 = blockIdx.y*32;
  const cplx* ip = in  + (size_t)c*PLANE;
  cplx*       op = out + (size_t)c*PLANE;
  int tx = threadIdx.x, ty = threadIdx.y;      // (32,8)
  for (int dy = 0; dy < 32; dy += 8)
    tile[ty+dy][tx] = ip[(size_t)(y0+ty+dy)*GRID_N + (x0+tx)];
  __syncthreads();
  for (int dy = 0; dy < 32; dy += 8)
    op[(size_t)(x0+ty+dy)*GRID_N + (y0+tx)] = tile[tx][ty+dy];
}

// planar [c][cell] -> coil-interleaved [cell][8 float2]  (fully coalesced)
__global__ void k_c2i(const float2* __restrict__ plan, float2* __restrict__ inter){
  int t = blockIdx.x*blockDim.x + threadIdx.x;
  if (t >= PLANE*NCOIL) return;
  int c = t & 7; int cell = t >> 3;
  inter[(size_t)cell*8 + c] = plan[(size_t)c*PLANE + cell];
}

// forward interp + lambda blend: thread = (sample, coil-pair)
__global__ __launch_bounds__(256) void k_fwd(
    const float* __restrict__ ktraj, const float* __restrict__ yre,
    const float* __restrict__ yim, const float* __restrict__ lraw,
    const float4* __restrict__ KTi4, float4* __restrict__ kdc4){
  int t = blockIdx.x*blockDim.x + threadIdx.x;
  if (t >= NK*4) return;
  int k = t >> 2, p = t & 3;

  int iy[JW], ix[JW]; float wy[JW], wx[JW];
  {
    float tm = ktraj[k] * KSCALE;
    int base = (int)floorf(tm - 3.0f);
    #pragma unroll
    for (int j = 1; j <= JW; ++j){
      int fidx = base + j;
      wy[j-1] = kb_w(tm - (float)fidx);
      iy[j-1] = fidx & (GRID_N-1);
    }
  }
  {
    float tm = ktraj[NK + k] * KSCALE;
    int base = (int)floorf(tm - 3.0f);
    #pragma unroll
    for (int j = 1; j <= JW; ++j){
      int fidx = base + j;
      wx[j-1] = kb_w(tm - (float)fidx);
      ix[j-1] = fidx & (GRID_N-1);
    }
  }

  float ax=0.f, ay=0.f, az=0.f, aw=0.f;
  #pragma unroll
  for (int jx = 0; jx < JW; ++jx){
    int ox = ix[jx]*GRID_N;
    #pragma unroll
    for (int jy = 0; jy < JW; ++jy){
      float w2 = wx[jx]*wy[jy];
      float4 v = KTi4[(size_t)(ox + iy[jy])*4 + p];
      ax += w2*v.x; ay += w2*v.y; az += w2*v.z; aw += w2*v.w;
    }
  }
  float lam = 1.0f/(1.0f + __expf(-lraw[0]));
  float oml = 1.0f - lam;
  int c0 = 2*p;
  float4 o;
  o.x = lam*ax + oml*yre[(size_t)c0*NK + k];
  o.y = lam*ay + oml*yim[(size_t)c0*NK + k];
  o.z = lam*az + oml*yre[(size_t)(c0+1)*NK + k];
  o.w = lam*aw + oml*yim[(size_t)(c0+1)*NK + k];
  kdc4[(size_t)k*4 + p] = o;
}

// 2D histogram over (column, y-base-class) bins
__global__ void k_hist2(const float* __restrict__ ktraj, unsigned* __restrict__ hist2){
  int k = blockIdx.x*blockDim.x + threadIdx.x;
  if (k >= NK) return;
  float tmy = ktraj[k] * KSCALE;
  int by = ((int)floorf(tmy - 3.0f)) & (GRID_N-1);
  float tmx = ktraj[NK + k] * KSCALE;
  int bx = (int)floorf(tmx - 3.0f);
  #pragma unroll
  for (int j = 1; j <= JW; ++j){
    int cj = (bx + j) & (GRID_N-1);
    atomicAdd(&hist2[cj*GRID_N + by], 1u);
  }
}

// per-column exclusive scan of 512 by-class counts; emits column totals
__global__ void k_colscan(const unsigned* __restrict__ hist2,
                          unsigned* __restrict__ binOff,
                          unsigned* __restrict__ colTotal){
  __shared__ unsigned s[GRID_N];
  int col = blockIdx.x, t = threadIdx.x;
  unsigned mine = hist2[col*GRID_N + t];
  s[t] = mine;
  __syncthreads();
  for (int off = 1; off < GRID_N; off <<= 1){
    unsigned add = (t >= off) ? s[t - off] : 0u;
    __syncthreads();
    s[t] += add;
    __syncthreads();
  }
  binOff[col*GRID_N + t] = s[t] - mine;        // exclusive within column
  if (t == GRID_N-1) colTotal[col] = s[t];
}

// scan 512 column totals -> column bases (+ grand total at [512])
__global__ void k_scanCT(const unsigned* __restrict__ colTotal,
                         unsigned* __restrict__ colBase){
  __shared__ unsigned s[GRID_N];
  int t = threadIdx.x;
  unsigned mine = colTotal[t];
  s[t] = mine;
  __syncthreads();
  for (int off = 1; off < GRID_N; off <<= 1){
    unsigned add = (t >= off) ? s[t - off] : 0u;
    __syncthreads();
    s[t] += add;
    __syncthreads();
  }
  colBase[t] = s[t] - mine;
  if (t == GRID_N-1) colBase[GRID_N] = s[t];
}

// binOff[i] += colBase[col]; sentinel at NBIN = grand total
__global__ void k_addbase(unsigned* __restrict__ binOff,
                          const unsigned* __restrict__ colBase){
  int i = blockIdx.x*blockDim.x + threadIdx.x;
  if (i > NBIN) return;
  if (i == NBIN){ binOff[i] = colBase[GRID_N]; return; }
  binOff[i] += colBase[i >> 9];
}

// place 16B records binned by (column, by):
// rec = { bf16(wx*wy1)|bf16(wx*wy2)<<16, .., (kk<<9)|by }
__global__ void k_place(const float* __restrict__ ktraj,
                        const unsigned* __restrict__ binOff,
                        unsigned* __restrict__ cnt2,
                        uint4* __restrict__ recs){
  int k = blockIdx.x*blockDim.x + threadIdx.x;
  if (k >= NK) return;
  float tmy = ktraj[k] * KSCALE;
  int by0 = (int)floorf(tmy - 3.0f);
  int by = by0 & (GRID_N-1);
  float wy[JW];
  #pragma unroll
  for (int j = 1; j <= JW; ++j) wy[j-1] = kb_w(tmy - (float)(by0 + j));

  float tmx = ktraj[NK + k] * KSCALE;
  int bx = (int)floorf(tmx - 3.0f);
  unsigned tag = ((unsigned)k << 9) | (unsigned)by;
  #pragma unroll
  for (int j = 1; j <= JW; ++j){
    int cj = (bx + j) & (GRID_N-1);
    float wx = kb_w(tmx - (float)(bx + j));
    uint4 rec;
    rec.x = bf16_of(wx*wy[0]) | (bf16_of(wx*wy[1]) << 16);
    rec.y = bf16_of(wx*wy[2]) | (bf16_of(wx*wy[3]) << 16);
    rec.z = bf16_of(wx*wy[4]) | (bf16_of(wx*wy[5]) << 16);
    rec.w = tag;
    int bin = cj*GRID_N + by;
    unsigned pos = binOff[bin] + atomicAdd(&cnt2[bin], 1u);
    recs[pos] = rec;
  }
}

// adjoint gridding, cooperative-window kernel, MERGED q-halves (r18).
// block = column (grid 512), 512 threads (8 waves); lane = (slot 0..3,
// q 0..15): 32 records in flight, each record visited ONCE, its full 64B
// kdc line read by its slot's 16 q-lanes. Slot-reduce = 2 shfl levels.
// Windows sequential; fold by 256 threads into 528x16 accumulator.
// Writeback PLANAR: q = coil*2 + (re/im).
__global__ __launch_bounds__(512) void k_adj(
    const uint4* __restrict__ recs, const unsigned* __restrict__ binOff,
    const float* __restrict__ kdcf, cplx* __restrict__ Hp){
  __shared__ float accs[ACCROWS*16];           // 33 KB
  __shared__ float part[8][16][16];            // 8 KB partial tiles
  const int col = blockIdx.x;
  const int tid = threadIdx.x;
  const int wave = tid >> 6, lane = tid & 63;
  const int slot = lane >> 4, q = lane & 15;
  for (int i = tid; i < ACCROWS*16; i += 512) accs[i] = 0.f;
  __syncthreads();

  const unsigned* bo = binOff + (size_t)col*GRID_N;

  for (int wi = 0; wi < NWIN; ++wi){
    int b0 = wi*WSZ;
    int b1 = b0 + WSZ; if (b1 > GRID_N) b1 = GRID_N;
    unsigned s = bo[b0];
    unsigned e = bo[b1];
    if (s == e) continue;                      // uniform across block

    float a0=0.f,a1=0.f,a2=0.f,a3=0.f,a4=0.f,a5=0.f,a6=0.f,a7=0.f;
    float a8=0.f,a9=0.f,a10=0.f,a11=0.f,a12=0.f,a13=0.f,a14=0.f,a15=0.f;

    for (unsigned base = s + (unsigned)wave*4; base < e; base += 32){
      unsigned e0 = base + (unsigned)slot;
      uint4 rc = recs[e0];                     // may over-read; guarded below
      float vv = 0.f;
      if (e0 < e){
        unsigned kk = (rc.w >> 9) & (NK-1);
        vv = kdcf[(size_t)kk*16 + q];
      }
      float w1 = bf_lo(rc.x), w2 = bf_hi(rc.x);
      float w3 = bf_lo(rc.y), w4 = bf_hi(rc.y);
      float w5 = bf_lo(rc.z), w6 = bf_hi(rc.z);
      int off = (int)(rc.w & (GRID_N-1)) - b0; // 0..10
      #pragma unroll
      for (int r = 0; r < 16; ++r){
        int idx = r - off;                     // tap index 0..5 = w_{idx+1}
        float wlo = (idx < 2) ? w1 : ((idx < 4) ? w3 : w5);
        float whi = (idx < 2) ? w2 : ((idx < 4) ? w4 : w6);
        float w = (idx & 1) ? whi : wlo;
        w = ((unsigned)idx < 6u) ? w : 0.f;
        float contrib = w * vv;
        if (r==0) a0+=contrib; else if (r==1) a1+=contrib;
        else if (r==2) a2+=contrib; else if (r==3) a3+=contrib;
        else if (r==4) a4+=contrib; else if (r==5) a5+=contrib;
        else if (r==6) a6+=contrib; else if (r==7) a7+=contrib;
        else if (r==8) a8+=contrib; else if (r==9) a9+=contrib;
        else if (r==10) a10+=contrib; else if (r==11) a11+=contrib;
        else if (r==12) a12+=contrib; else if (r==13) a13+=contrib;
        else if (r==14) a14+=contrib; else a15+=contrib;
      }
    }

    // slot-reduce: slot = lane bits 4..5 -> xor masks 16, 32
    #pragma unroll
    for (int m = 16; m <= 32; m <<= 1){
      a0 += __shfl_xor(a0, m);  a1 += __shfl_xor(a1, m);
      a2 += __shfl_xor(a2, m);  a3 += __shfl_xor(a3, m);
      a4 += __shfl_xor(a4, m);  a5 += __shfl_xor(a5, m);
      a6 += __shfl_xor(a6, m);  a7 += __shfl_xor(a7, m);
      a8 += __shfl_xor(a8, m);  a9 += __shfl_xor(a9, m);
      a10 += __shfl_xor(a10, m); a11 += __shfl_xor(a11, m);
      a12 += __shfl_xor(a12, m); a13 += __shfl_xor(a13, m);
      a14 += __shfl_xor(a14, m); a15 += __shfl_xor(a15, m);
    }
    if (slot == 0){                            // lanes 0..15, q = lane
      part[wave][0][q]  = a0;  part[wave][1][q]  = a1;
      part[wave][2][q]  = a2;  part[wave][3][q]  = a3;
      part[wave][4][q]  = a4;  part[wave][5][q]  = a5;
      part[wave][6][q]  = a6;  part[wave][7][q]  = a7;
      part[wave][8][q]  = a8;  part[wave][9][q]  = a9;
      part[wave][10][q] = a10; part[wave][11][q] = a11;
      part[wave][12][q] = a12; part[wave][13][q] = a13;
      part[wave][14][q] = a14; part[wave][15][q] = a15;
    }
    __syncthreads();
    if (tid < 256){
      int r = tid >> 4, qq = tid & 15;
      float sum = part[0][r][qq] + part[1][r][qq] + part[2][r][qq]
                + part[3][r][qq] + part[4][r][qq] + part[5][r][qq]
                + part[6][r][qq] + part[7][r][qq];
      accs[(size_t)(b0+1+r)*16 + qq] += sum;
    }
    __syncthreads();
  }

  // fold wrap rows (512..527 -> 0..15); write Hp PLANAR:
  // q = coil*2 + comp; x-major cell (col, y)
  for (int i = tid; i < GRID_N*8; i += 512){
    int j = i >> 9, y = i & (GRID_N-1);
    float re = accs[y*16 + 2*j]     + ((y < 16) ? accs[(GRID_N+y)*16 + 2*j]   : 0.f);
    float im = accs[y*16 + 2*j + 1] + ((y < 16) ? accs[(GRID_N+y)*16 + 2*j+1] : 0.f);
    cplx o; o.x = re; o.y = im;
    Hp[(size_t)j*PLANE + (size_t)col*GRID_N + y] = o;
  }
}

// crop, apodize, conj(smaps) coil-combine; ACCUMULATES into out
__global__ void k_final(const cplx* __restrict__ Bg, const float* __restrict__ sr,
                        const float* __restrict__ si, const float* __restrict__ sc,
                        float* __restrict__ out, int pairs){
  int idx = blockIdx.x*blockDim.x + threadIdx.x;   // y*256+x
  if (idx >= IM_N*IM_N) return;
  int y = idx >> 8, x = idx & 255;
  float s2 = sc[y]*sc[x];
  float ax = 0.f, ay = 0.f;
  #pragma unroll
  for (int c = 0; c < NCOIL; ++c){
    cplx v = Bg[(size_t)c*PLANE + y*GRID_N + x];
    int gi = (c << 16) | idx;
    float rr = sr[gi], ii = si[gi];
    ax += rr*v.x + ii*v.y;      // conj(s)*v real
    ay += rr*v.y - ii*v.x;      // conj(s)*v imag
  }
  if (pairs){
    out[idx*2]   += ax * s2;
    out[idx*2+1] += ay * s2;
  } else {
    out[idx]     += ax * s2;
  }
}

// ---------------- fallback (round-2 validated fused atomic path) -------------
__global__ void k_zero4(float4* p, int n4){
  int i = blockIdx.x*blockDim.x + threadIdx.x;
  if (i < n4) p[i] = make_float4(0.f,0.f,0.f,0.f);
}

__global__ void k_fill_fb(const float* __restrict__ ximg, const float* __restrict__ sr,
                          const float* __restrict__ si, const float* __restrict__ sc,
                          cplx* __restrict__ A){
  int idx = blockIdx.x*blockDim.x + threadIdx.x;
  if (idx >= NCOIL*IM_N*IM_N) return;
  int c = idx >> 16;
  int pix = idx & 65535;
  int y = pix >> 8, x = pix & 255;
  float v = ximg[pix] * sc[y]*sc[x];
  cplx o; o.x = v * sr[idx]; o.y = v * si[idx];
  A[(size_t)c*PLANE + y*GRID_N + x] = o;
}

__global__ void k_gather_scatter_fb(const float* __restrict__ ktraj,
                                    const float* __restrict__ yre,
                                    const float* __restrict__ yim,
                                    const float* __restrict__ lraw,
                                    const cplx* __restrict__ KT,
                                    float* __restrict__ HT){
  int k = blockIdx.x*blockDim.x + threadIdx.x;
  if (k >= NK) return;
  float lam   = 1.0f/(1.0f + __expf(-lraw[0]));
  float omlam = 1.0f - lam;
  int iy[JW], ix[JW]; float wy[JW], wx[JW];
  {
    float tm = ktraj[k] * KSCALE;
    int base = (int)floorf(tm - 3.0f);
    #pragma unroll
    for (int j = 1; j <= JW; ++j){
      wy[j-1] = kb_w(tm - (float)(base+j));
      iy[j-1] = (base+j) & (GRID_N-1);
    }
  }
  {
    float tm = ktraj[NK + k] * KSCALE;
    int base = (int)floorf(tm - 3.0f);
    #pragma unroll
    for (int j = 1; j <= JW; ++j){
      wx[j-1] = kb_w(tm - (float)(base+j));
      ix[j-1] = (base+j) & (GRID_N-1);
    }
  }
  float accx[NCOIL], accy[NCOIL];
  #pragma unroll
  for (int c = 0; c < NCOIL; ++c){ accx[c]=0.f; accy[c]=0.f; }
  #pragma unroll
  for (int jx = 0; jx < JW; ++jx){
    int ox = ix[jx]*GRID_N;
    #pragma unroll
    for (int jy = 0; jy < JW; ++jy){
      float w2 = wx[jx]*wy[jy];
      size_t o = (size_t)(ox + iy[jy]);
      #pragma unroll
      for (int c = 0; c < NCOIL; ++c){
        cplx v = KT[(size_t)c*PLANE + o];
        accx[c] += w2*v.x; accy[c] += w2*v.y;
      }
    }
  }
  float kdx[NCOIL], kdy[NCOIL];
  #pragma unroll
  for (int c = 0; c < NCOIL; ++c){
    kdx[c] = lam*accx[c] + omlam*yre[(size_t)c*NK + k];
    kdy[c] = lam*accy[c] + omlam*yim[(size_t)c*NK + k];
  }
  #pragma unroll
  for (int jx = 0; jx < JW; ++jx){
    int ox = ix[jx]*GRID_N;
    #pragma unroll
    for (int jy = 0; jy < JW; ++jy){
      float w2 = wx[jx]*wy[jy];
      size_t o = (size_t)(ox + iy[jy]);
      #pragma unroll
      for (int c = 0; c < NCOIL; ++c){
        float* dst = HT + ((size_t)c*PLANE + o)*2;
        atomicAdd(dst,   w2*kdx[c]);
        atomicAdd(dst+1, w2*kdy[c]);
      }
    }
  }
}

extern "C" void kernel_launch(void* const* d_in, const int* in_sizes, int n_in,
                              void* d_out, int out_size, void* d_ws, size_t ws_size,
                              hipStream_t stream) {
  const float* ximg  = (const float*)d_in[0];
  const float* yre   = (const float*)d_in[1];
  const float* yim   = (const float*)d_in[2];
  const float* sre   = (const float*)d_in[3];
  const float* sim   = (const float*)d_in[4];
  const float* ktraj = (const float*)d_in[5];
  const float* lraw  = (const float*)d_in[6];
  float* out = (float*)d_out;

  char* ws = (char*)d_ws;
  const size_t REG = 16777216;                 // one planar grid: 512*512*8B*8
  int pairs = (out_size >= 2*IM_N*IM_N) ? 1 : 0;

  // primary layout (50.34 MB):
  //  R0 [0,REG): A planar (fwd fft) -> { kdc 8MB | hist2 1MB | cnt2 1MB |
  //              binOff 1MB+4 | colTot | colBase } -> imgF planar
  //  R1 [REG,2REG): Bb planar -> recs (786432 x 16B = 12.6MB)
  //  R2 [2REG,3REG): KTi interleaved -> Hp planar (k_adj out, ifft in-place)
  //  [3REG,...): sc (4KB)
  const size_t need = 3*REG + 4096;

  if (ws_size >= need){
    cplx*     A     = (cplx*)ws;                           // R0
    cplx*     Bb    = (cplx*)(ws + REG);                   // R1
    float4*   KTi4  = (float4*)(ws + 2*REG);               // R2
    float*    sc    = (float*)(ws + 3*REG);
    float4*   kdc4  = (float4*)ws;                         // R0 +0   (8MB)
    unsigned* hist2 = (unsigned*)(ws + 8388608);           // R0 +8M  (1MB)
    unsigned* cnt2  = (unsigned*)(ws + 9437184);           // R0 +9M  (1MB)
    unsigned* binOff= (unsigned*)(ws + 10485760);          // R0 +10M (1MB+4)
    unsigned* colTot= (unsigned*)(ws + 11538432);          // 2KB
    unsigned* colBase=(unsigned*)(ws + 11540480);          // 2052B
    uint4*    recs  = (uint4*)(ws + REG);                  // R1 (12.6MB)
    cplx*     Hp    = (cplx*)(ws + 2*REG);                 // R2 (over dead KTi)
    cplx*     imgF  = (cplx*)ws;                           // R0 (after k_adj)

    k_sc_table<<<1,256,0,stream>>>(sc);

    // fused pad+apodize+smap + fwd fft rows over x -> A planar [c][y][x]
    k_fft_fill<<<NCOIL*GRID_N,256,0,stream>>>(ximg, sre, sim, sc, A);
    k_transpose<<<dim3(16,16,NCOIL),dim3(32,8),0,stream>>>(A, Bb);
    k_fft_rows<-1><<<NCOIL*GRID_N,256,0,stream>>>(Bb, 1.0f/(float)GRID_N);

    k_c2i<<<(PLANE*NCOIL+255)/256,256,0,stream>>>((const float2*)Bb, (float2*)KTi4);

    // forward interp + blend -> kdc (overlays dead A region)
    k_fwd<<<(NK*4+255)/256,256,0,stream>>>(ktraj, yre, yim, lraw, KTi4, kdc4);

    // (col, by) binning: 2D histogram + hierarchical scan + placement
    k_zero1<<<(2*NBIN+255)/256,256,0,stream>>>((float*)hist2, 2*NBIN); // hist2+cnt2
    k_hist2<<<NK/256,256,0,stream>>>(ktraj, hist2);
    k_colscan<<<GRID_N,GRID_N,0,stream>>>(hist2, binOff, colTot);
    k_scanCT<<<1,GRID_N,0,stream>>>(colTot, colBase);
    k_addbase<<<(NBIN+256)/256,256,0,stream>>>(binOff, colBase);
    k_place<<<NK/256,256,0,stream>>>(ktraj, binOff, cnt2, recs);

    // adjoint gridding: merged-halves cooperative windows, planar writeback
    k_adj<<<GRID_N,512,0,stream>>>(recs, binOff, (const float*)kdc4, Hp);

    // adjoint ifft2*512: rows over y (Hp in-place), crop-aware transpose
    // (only y_img<256 rows), ifft over x on 256 rows/coil with x<256 write
    k_fft_rows<+1><<<NCOIL*GRID_N,256,0,stream>>>(Hp, 1.0f);
    k_transpose<<<dim3(8,16,NCOIL),dim3(32,8),0,stream>>>(Hp, imgF);
    k_fft_rows_c<<<NCOIL*IM_N,256,0,stream>>>(imgF, 1.0f/(float)GRID_N);

    k_zero1<<<(out_size+255)/256,256,0,stream>>>(out, out_size);
    k_final<<<(IM_N*IM_N+255)/256,256,0,stream>>>(imgF, sre, sim, sc, out, pairs);
  } else {
    // fallback: round-2 validated path (needs 33.6 MB)
    float* sc = (float*)ws;
    cplx*  A  = (cplx*)(ws + 4096);
    cplx*  Bb = (cplx*)(ws + 4096 + REG);
    const int n4 = NCOIL*PLANE*2/4;

    k_sc_table<<<1,256,0,stream>>>(sc);
    k_zero4<<<(n4+255)/256,256,0,stream>>>((float4*)A, n4);
    k_fill_fb<<<(NCOIL*IM_N*IM_N+255)/256,256,0,stream>>>(ximg, sre, sim, sc, A);
    k_fft_rows<-1><<<NCOIL*GRID_N,256,0,stream>>>(A, 1.0f);
    k_transpose<<<dim3(16,16,NCOIL),dim3(32,8),0,stream>>>(A, Bb);
    k_fft_rows<-1><<<NCOIL*GRID_N,256,0,stream>>>(Bb, 1.0f/(float)GRID_N);
    k_zero4<<<(n4+255)/256,256,0,stream>>>((float4*)A, n4);
    k_gather_scatter_fb<<<(NK+255)/256,256,0,stream>>>(ktraj, yre, yim, lraw, Bb, (float*)A);
    k_fft_rows<+1><<<NCOIL*GRID_N,256,0,stream>>>(A, 1.0f);
    k_transpose<<<dim3(16,16,NCOIL),dim3(32,8),0,stream>>>(A, Bb);
    k_fft_rows<+1><<<NCOIL*GRID_N,256,0,stream>>>(Bb, 1.0f/(float)GRID_N);
    k_zero1<<<(out_size+255)/256,256,0,stream>>>(out, out_size);
    k_final<<<(IM_N*IM_N+255)/256,256,0,stream>>>(Bb, sre, sim, sc, out, pairs);
  }
}

// Round 19
// 383.993 us; speedup vs baseline: 1.0363x; 1.0363x over previous
//
#include <hip/hip_runtime.h>
#include <math.h>

#define GRID_N 512
#define IM_N   256
#define NCOIL  8
#define NK     131072
#define PLANE  (GRID_N*GRID_N)
#define JW     6
#define NBIN   (GRID_N*GRID_N/512*512)  /* 262144 (col,by) bins */
#define WSZ    11
#define NWIN   47                        /* ceil(512/11) */
#define ACCROWS 528
#define BETA_F 13.8551003f   /* pi*sqrt((6/2)^2*(2-0.5)^2 - 0.8) */
#define KSCALE 81.48733086305042f  /* 512/(2*pi) */

struct cplx { float x, y; };

__device__ __forceinline__ float bessel_i0f(float x){
  // Abramowitz & Stegun 9.8.1 / 9.8.2, rel err < 2e-7
  if (x < 3.75f){
    float t = x*(1.0f/3.75f); t = t*t;
    return 1.0f + t*(3.5156229f + t*(3.0899424f + t*(1.2067492f
           + t*(0.2659732f + t*(0.0360768f + t*0.0045813f)))));
  } else {
    float t = 3.75f/x;
    float p = 0.39894228f + t*(0.01328592f + t*(0.00225319f + t*(-0.00157565f
            + t*(0.00916281f + t*(-0.02057706f + t*(0.02635537f
            + t*(-0.01647633f + t*0.00392377f)))))));
    return p * __expf(x) * rsqrtf(x);
  }
}

__device__ __forceinline__ float kb_w(float u){   // 1-axis KB weight, |u|<=3
  float uu = u*(1.0f/3.0f);
  float q = fmaxf(1.0f - uu*uu, 0.0f);
  return bessel_i0f(BETA_F*sqrtf(q)) * (1.0f/6.0f);
}

__device__ __forceinline__ unsigned bf16_of(float f){
  unsigned u = __float_as_uint(f);
  return (u + 0x8000u) >> 16;
}
__device__ __forceinline__ float bf_lo(unsigned w){ return __uint_as_float(w << 16); }
__device__ __forceinline__ float bf_hi(unsigned w){ return __uint_as_float(w & 0xFFFF0000u); }

// Kaiser-Bessel apodization correction row table sc[256]
__global__ void k_sc_table(float* sc){
  int i = threadIdx.x;
  if (i >= IM_N) return;
  float n  = (i - IM_N*0.5f) * (1.0f/GRID_N);
  float pj = 3.14159265358979f * (float)JW * n;
  float t  = BETA_F*BETA_F - pj*pj;
  float sp = sqrtf(fmaxf(t, 1e-12f));
  float sn = sqrtf(fmaxf(-t, 1e-12f));
  float ft = (t > 0.0f) ? (sinhf(sp)/sp) : (sinf(sn)/sn);
  float sc0 = sinhf(BETA_F)/BETA_F;
  sc[i] = sc0/ft;
}

__global__ void k_zero1(float* p, int n){
  int i = blockIdx.x*blockDim.x + threadIdx.x;
  if (i < n) p[i] = 0.f;
}

// FUSED: pad + apodize + smap-multiply + fwd 512-pt FFT row (DIR=-1, scale 1)
// block = c*512+y; rows y>=256 are identically zero -> direct zero store.
__global__ void k_fft_fill(const float* __restrict__ ximg, const float* __restrict__ sr,
                           const float* __restrict__ si, const float* __restrict__ sc,
                           cplx* __restrict__ buf){
  __shared__ cplx lds[GRID_N];
  int blk = blockIdx.x;                        // c*512 + y
  int c = blk >> 9, y = blk & (GRID_N-1);
  cplx* p = buf + (size_t)blk * GRID_N;
  int tid = threadIdx.x;
  if (y >= IM_N){
    cplx z; z.x = 0.f; z.y = 0.f;
    for (int i = tid; i < GRID_N; i += 256) p[i] = z;
    return;
  }
  float scy = sc[y];
  for (int i = tid; i < GRID_N; i += 256){
    int r = __brev((unsigned)i) >> 23;
    cplx v; v.x = 0.f; v.y = 0.f;
    if (i < IM_N){
      float vv = ximg[(y<<8)|i] * scy * sc[i];
      int gi = (c << 16) | (y << 8) | i;
      v.x = vv * sr[gi]; v.y = vv * si[gi];
    }
    lds[r] = v;
  }
  __syncthreads();
  for (int half = 1; half < GRID_N; half <<= 1){
    int j = tid & (half-1);
    int k = ((tid & ~(half-1)) << 1) | j;
    float ang = -3.14159265358979f * (float)j / (float)half;
    float sw, cw; __sincosf(ang, &sw, &cw);
    cplx u = lds[k];
    cplx v = lds[k+half];
    cplx t; t.x = v.x*cw - v.y*sw; t.y = v.x*sw + v.y*cw;
    lds[k].x      = u.x + t.x; lds[k].y      = u.y + t.y;
    lds[k+half].x = u.x - t.x; lds[k+half].y = u.y - t.y;
    __syncthreads();
  }
  for (int i = tid; i < GRID_N; i += 256) p[i] = lds[i];
}

// in-place 512-pt radix-2 FFT on each contiguous row; DIR=-1 fwd, +1 inv(unnorm)
template<int DIR>
__global__ void k_fft_rows(cplx* __restrict__ buf, float scale){
  __shared__ cplx lds[GRID_N];
  cplx* p = buf + (size_t)blockIdx.x * GRID_N;
  int tid = threadIdx.x;                       // 256 threads
  for (int i = tid; i < GRID_N; i += 256){
    int r = __brev((unsigned)i) >> 23;         // 9-bit reverse
    lds[r] = p[i];
  }
  __syncthreads();
  for (int half = 1; half < GRID_N; half <<= 1){
    int j = tid & (half-1);
    int k = ((tid & ~(half-1)) << 1) | j;
    float ang = (float)DIR * 3.14159265358979f * (float)j / (float)half;
    float sw, cw; __sincosf(ang, &sw, &cw);
    cplx u = lds[k];
    cplx v = lds[k+half];
    cplx t; t.x = v.x*cw - v.y*sw; t.y = v.x*sw + v.y*cw;
    lds[k].x      = u.x + t.x; lds[k].y      = u.y + t.y;
    lds[k+half].x = u.x - t.x; lds[k+half].y = u.y - t.y;
    __syncthreads();
  }
  for (int i = tid; i < GRID_N; i += 256){
    cplx v = lds[i]; v.x *= scale; v.y *= scale; p[i] = v;
  }
}

// crop variant: 256 rows per coil (y<256), inverse FFT over x, write x<256 only
__global__ void k_fft_rows_c(cplx* __restrict__ buf, float scale){
  __shared__ cplx lds[GRID_N];
  int b = blockIdx.x;                          // c*256 + y
  int c = b >> 8, y = b & (IM_N-1);
  cplx* p = buf + (size_t)c*PLANE + (size_t)y*GRID_N;
  int tid = threadIdx.x;
  for (int i = tid; i < GRID_N; i += 256){
    int r = __brev((unsigned)i) >> 23;
    lds[r] = p[i];
  }
  __syncthreads();
  for (int half = 1; half < GRID_N; half <<= 1){
    int j = tid & (half-1);
    int k = ((tid & ~(half-1)) << 1) | j;
    float ang = 3.14159265358979f * (float)j / (float)half;
    float sw, cw; __sincosf(ang, &sw, &cw);
    cplx u = lds[k];
    cplx v = lds[k+half];
    cplx t; t.x = v.x*cw - v.y*sw; t.y = v.x*sw + v.y*cw;
    lds[k].x      = u.x + t.x; lds[k].y      = u.y + t.y;
    lds[k+half].x = u.x - t.x; lds[k+half].y = u.y - t.y;
    __syncthreads();
  }
  for (int i = tid; i < IM_N; i += 256){       // crop: only x<256 consumed
    cplx v = lds[i]; v.x *= scale; v.y *= scale; p[i] = v;
  }
}

// 512x512 (or partial) tile transpose per coil plane, out[X][Y] = in[Y][X]
__global__ void k_transpose(const cplx* __restrict__ in, cplx* __restrict__ out){
  __shared__ cplx tile[32][33];
  int c  = blockIdx.z;
  int x0 = blockIdx.x*32, y0 = blockIdx.y*32;
  const cplx* ip = in  + (size_t)c*PLANE;
  cplx*       op = out + (size_t)c*PLANE;
  int tx = threadIdx.x, ty = threadIdx.y;      // (32,8)
  for (int dy = 0; dy < 32; dy += 8)
    tile[ty+dy][tx] = ip[(size_t)(y0+ty+dy)*GRID_N + (x0+tx)];
  __syncthreads();
  for (int dy = 0; dy < 32; dy += 8)
    op[(size_t)(x0+ty+dy)*GRID_N + (y0+tx)] = tile[tx][ty+dy];
}

// planar [c][cell] -> coil-interleaved [cell][8 float2]  (fully coalesced)
__global__ void k_c2i(const float2* __restrict__ plan, float2* __restrict__ inter){
  int t = blockIdx.x*blockDim.x + threadIdx.x;
  if (t >= PLANE*NCOIL) return;
  int c = t & 7; int cell = t >> 3;
  inter[(size_t)cell*8 + c] = plan[(size_t)c*PLANE + cell];
}

// forward interp + lambda blend: thread = (sample, coil-pair)
__global__ __launch_bounds__(256) void k_fwd(
    const float* __restrict__ ktraj, const float* __restrict__ yre,
    const float* __restrict__ yim, const float* __restrict__ lraw,
    const float4* __restrict__ KTi4, float4* __restrict__ kdc4){
  int t = blockIdx.x*blockDim.x + threadIdx.x;
  if (t >= NK*4) return;
  int k = t >> 2, p = t & 3;

  int iy[JW], ix[JW]; float wy[JW], wx[JW];
  {
    float tm = ktraj[k] * KSCALE;
    int base = (int)floorf(tm - 3.0f);
    #pragma unroll
    for (int j = 1; j <= JW; ++j){
      int fidx = base + j;
      wy[j-1] = kb_w(tm - (float)fidx);
      iy[j-1] = fidx & (GRID_N-1);
    }
  }
  {
    float tm = ktraj[NK + k] * KSCALE;
    int base = (int)floorf(tm - 3.0f);
    #pragma unroll
    for (int j = 1; j <= JW; ++j){
      int fidx = base + j;
      wx[j-1] = kb_w(tm - (float)fidx);
      ix[j-1] = fidx & (GRID_N-1);
    }
  }

  float ax=0.f, ay=0.f, az=0.f, aw=0.f;
  #pragma unroll
  for (int jx = 0; jx < JW; ++jx){
    int ox = ix[jx]*GRID_N;
    #pragma unroll
    for (int jy = 0; jy < JW; ++jy){
      float w2 = wx[jx]*wy[jy];
      float4 v = KTi4[(size_t)(ox + iy[jy])*4 + p];
      ax += w2*v.x; ay += w2*v.y; az += w2*v.z; aw += w2*v.w;
    }
  }
  float lam = 1.0f/(1.0f + __expf(-lraw[0]));
  float oml = 1.0f - lam;
  int c0 = 2*p;
  float4 o;
  o.x = lam*ax + oml*yre[(size_t)c0*NK + k];
  o.y = lam*ay + oml*yim[(size_t)c0*NK + k];
  o.z = lam*az + oml*yre[(size_t)(c0+1)*NK + k];
  o.w = lam*aw + oml*yim[(size_t)(c0+1)*NK + k];
  kdc4[(size_t)k*4 + p] = o;
}

// 2D histogram over (column, y-base-class) bins
__global__ void k_hist2(const float* __restrict__ ktraj, unsigned* __restrict__ hist2){
  int k = blockIdx.x*blockDim.x + threadIdx.x;
  if (k >= NK) return;
  float tmy = ktraj[k] * KSCALE;
  int by = ((int)floorf(tmy - 3.0f)) & (GRID_N-1);
  float tmx = ktraj[NK + k] * KSCALE;
  int bx = (int)floorf(tmx - 3.0f);
  #pragma unroll
  for (int j = 1; j <= JW; ++j){
    int cj = (bx + j) & (GRID_N-1);
    atomicAdd(&hist2[cj*GRID_N + by], 1u);
  }
}

// per-column exclusive scan of 512 by-class counts; emits column totals
__global__ void k_colscan(const unsigned* __restrict__ hist2,
                          unsigned* __restrict__ binOff,
                          unsigned* __restrict__ colTotal){
  __shared__ unsigned s[GRID_N];
  int col = blockIdx.x, t = threadIdx.x;
  unsigned mine = hist2[col*GRID_N + t];
  s[t] = mine;
  __syncthreads();
  for (int off = 1; off < GRID_N; off <<= 1){
    unsigned add = (t >= off) ? s[t - off] : 0u;
    __syncthreads();
    s[t] += add;
    __syncthreads();
  }
  binOff[col*GRID_N + t] = s[t] - mine;        // exclusive within column
  if (t == GRID_N-1) colTotal[col] = s[t];
}

// scan 512 column totals -> column bases (+ grand total at [512])
__global__ void k_scanCT(const unsigned* __restrict__ colTotal,
                         unsigned* __restrict__ colBase){
  __shared__ unsigned s[GRID_N];
  int t = threadIdx.x;
  unsigned mine = colTotal[t];
  s[t] = mine;
  __syncthreads();
  for (int off = 1; off < GRID_N; off <<= 1){
    unsigned add = (t >= off) ? s[t - off] : 0u;
    __syncthreads();
    s[t] += add;
    __syncthreads();
  }
  colBase[t] = s[t] - mine;
  if (t == GRID_N-1) colBase[GRID_N] = s[t];
}

// binOff[i] += colBase[col]; sentinel at NBIN = grand total
__global__ void k_addbase(unsigned* __restrict__ binOff,
                          const unsigned* __restrict__ colBase){
  int i = blockIdx.x*blockDim.x + threadIdx.x;
  if (i > NBIN) return;
  if (i == NBIN){ binOff[i] = colBase[GRID_N]; return; }
  binOff[i] += colBase[i >> 9];
}

// place 16B records binned by (column, by):
// rec = { bf16(wx*wy1)|bf16(wx*wy2)<<16, .., (kk<<9)|by }
__global__ void k_place(const float* __restrict__ ktraj,
                        const unsigned* __restrict__ binOff,
                        unsigned* __restrict__ cnt2,
                        uint4* __restrict__ recs){
  int k = blockIdx.x*blockDim.x + threadIdx.x;
  if (k >= NK) return;
  float tmy = ktraj[k] * KSCALE;
  int by0 = (int)floorf(tmy - 3.0f);
  int by = by0 & (GRID_N-1);
  float wy[JW];
  #pragma unroll
  for (int j = 1; j <= JW; ++j) wy[j-1] = kb_w(tmy - (float)(by0 + j));

  float tmx = ktraj[NK + k] * KSCALE;
  int bx = (int)floorf(tmx - 3.0f);
  unsigned tag = ((unsigned)k << 9) | (unsigned)by;
  #pragma unroll
  for (int j = 1; j <= JW; ++j){
    int cj = (bx + j) & (GRID_N-1);
    float wx = kb_w(tmx - (float)(bx + j));
    uint4 rec;
    rec.x = bf16_of(wx*wy[0]) | (bf16_of(wx*wy[1]) << 16);
    rec.y = bf16_of(wx*wy[2]) | (bf16_of(wx*wy[3]) << 16);
    rec.z = bf16_of(wx*wy[4]) | (bf16_of(wx*wy[5]) << 16);
    rec.w = tag;
    int bin = cj*GRID_N + by;
    unsigned pos = binOff[bin] + atomicAdd(&cnt2[bin], 1u);
    recs[pos] = rec;
  }
}

// adjoint gridding, cooperative-window kernel (r17 structure, validated
// 235us/46% VALUBusy/62% occupancy). block = (column, q-half), 512 thr
// (8 waves); windows sequential, records strided across waves (64 in
// flight). Double-buffered partial tiles -> ONE barrier per window.
// Writeback PLANAR: local q-pair (2j,2j+1) = coil h*4+j (re,im).
__global__ __launch_bounds__(512) void k_adj(
    const uint4* __restrict__ recs, const unsigned* __restrict__ binOff,
    const float* __restrict__ kdcf, cplx* __restrict__ Hp){
  __shared__ float accs[ACCROWS*8];            // 16.5 KB (one q-half)
  __shared__ float part[2][8][16][8];          // 8 KB double-buffered partials
  const int col = blockIdx.x, h = blockIdx.y;
  const int tid = threadIdx.x;
  const int wave = tid >> 6, lane = tid & 63;
  const int slot = lane >> 3, q = lane & 7;
  for (int i = tid; i < ACCROWS*8; i += 512) accs[i] = 0.f;
  __syncthreads();

  const unsigned* bo = binOff + (size_t)col*GRID_N;
  const size_t qoff = (size_t)(h*8 + q);
  int pb = 0;

  for (int wi = 0; wi < NWIN; ++wi){
    int b0 = wi*WSZ;
    int b1 = b0 + WSZ; if (b1 > GRID_N) b1 = GRID_N;
    unsigned s = bo[b0];
    unsigned e = bo[b1];
    if (s == e) continue;                      // uniform across block

    float a0=0.f,a1=0.f,a2=0.f,a3=0.f,a4=0.f,a5=0.f,a6=0.f,a7=0.f;
    float a8=0.f,a9=0.f,a10=0.f,a11=0.f,a12=0.f,a13=0.f,a14=0.f,a15=0.f;

    for (unsigned base = s + (unsigned)wave*8; base < e; base += 64){
      unsigned e0 = base + (unsigned)slot;
      uint4 rc = recs[e0];                     // may over-read; guarded below
      float vv = 0.f;
      if (e0 < e){
        unsigned kk = (rc.w >> 9) & (NK-1);
        vv = kdcf[(size_t)kk*16 + qoff];
      }
      float w1 = bf_lo(rc.x), w2 = bf_hi(rc.x);
      float w3 = bf_lo(rc.y), w4 = bf_hi(rc.y);
      float w5 = bf_lo(rc.z), w6 = bf_hi(rc.z);
      int off = (int)(rc.w & (GRID_N-1)) - b0; // 0..10
      #pragma unroll
      for (int r = 0; r < 16; ++r){
        int idx = r - off;                     // tap index 0..5 = w_{idx+1}
        float wlo = (idx < 2) ? w1 : ((idx < 4) ? w3 : w5);
        float whi = (idx < 2) ? w2 : ((idx < 4) ? w4 : w6);
        float w = (idx & 1) ? whi : wlo;
        w = ((unsigned)idx < 6u) ? w : 0.f;
        float contrib = w * vv;
        if (r==0) a0+=contrib; else if (r==1) a1+=contrib;
        else if (r==2) a2+=contrib; else if (r==3) a3+=contrib;
        else if (r==4) a4+=contrib; else if (r==5) a5+=contrib;
        else if (r==6) a6+=contrib; else if (r==7) a7+=contrib;
        else if (r==8) a8+=contrib; else if (r==9) a9+=contrib;
        else if (r==10) a10+=contrib; else if (r==11) a11+=contrib;
        else if (r==12) a12+=contrib; else if (r==13) a13+=contrib;
        else if (r==14) a14+=contrib; else a15+=contrib;
      }
    }

    // wave slot-reduce: lane bits 3..5 are slot -> xor masks 8,16,32
    #pragma unroll
    for (int m = 8; m <= 32; m <<= 1){
      a0 += __shfl_xor(a0, m);  a1 += __shfl_xor(a1, m);
      a2 += __shfl_xor(a2, m);  a3 += __shfl_xor(a3, m);
      a4 += __shfl_xor(a4, m);  a5 += __shfl_xor(a5, m);
      a6 += __shfl_xor(a6, m);  a7 += __shfl_xor(a7, m);
      a8 += __shfl_xor(a8, m);  a9 += __shfl_xor(a9, m);
      a10 += __shfl_xor(a10, m); a11 += __shfl_xor(a11, m);
      a12 += __shfl_xor(a12, m); a13 += __shfl_xor(a13, m);
      a14 += __shfl_xor(a14, m); a15 += __shfl_xor(a15, m);
    }
    if (slot == 0){
      part[pb][wave][0][q]  = a0;  part[pb][wave][1][q]  = a1;
      part[pb][wave][2][q]  = a2;  part[pb][wave][3][q]  = a3;
      part[pb][wave][4][q]  = a4;  part[pb][wave][5][q]  = a5;
      part[pb][wave][6][q]  = a6;  part[pb][wave][7][q]  = a7;
      part[pb][wave][8][q]  = a8;  part[pb][wave][9][q]  = a9;
      part[pb][wave][10][q] = a10; part[pb][wave][11][q] = a11;
      part[pb][wave][12][q] = a12; part[pb][wave][13][q] = a13;
      part[pb][wave][14][q] = a14; part[pb][wave][15][q] = a15;
    }
    __syncthreads();                           // single barrier per window
    if (tid < 128){
      int r = tid >> 3, qq = tid & 7;
      float sum = part[pb][0][r][qq] + part[pb][1][r][qq]
                + part[pb][2][r][qq] + part[pb][3][r][qq]
                + part[pb][4][r][qq] + part[pb][5][r][qq]
                + part[pb][6][r][qq] + part[pb][7][r][qq];
      accs[(size_t)(b0+1+r)*8 + qq] += sum;
    }
    pb ^= 1;                                   // next window writes other buf
  }
  __syncthreads();                             // last fold before readback

  // fold wrap rows (512..527 -> 0..15); write Hp PLANAR:
  // local pair (2j, 2j+1) = coil h*4+j (re, im); x-major cell (col, y)
  for (int i = tid; i < GRID_N*4; i += 512){
    int j = i >> 9, y = i & (GRID_N-1);
    float re = accs[y*8 + 2*j]     + ((y < 16) ? accs[(GRID_N+y)*8 + 2*j]   : 0.f);
    float im = accs[y*8 + 2*j + 1] + ((y < 16) ? accs[(GRID_N+y)*8 + 2*j+1] : 0.f);
    cplx o; o.x = re; o.y = im;
    Hp[(size_t)(h*4 + j)*PLANE + (size_t)col*GRID_N + y] = o;
  }
}

// crop, apodize, conj(smaps) coil-combine; ACCUMULATES into out
__global__ void k_final(const cplx* __restrict__ Bg, const float* __restrict__ sr,
                        const float* __restrict__ si, const float* __restrict__ sc,
                        float* __restrict__ out, int pairs){
  int idx = blockIdx.x*blockDim.x + threadIdx.x;   // y*256+x
  if (idx >= IM_N*IM_N) return;
  int y = idx >> 8, x = idx & 255;
  float s2 = sc[y]*sc[x];
  float ax = 0.f, ay = 0.f;
  #pragma unroll
  for (int c = 0; c < NCOIL; ++c){
    cplx v = Bg[(size_t)c*PLANE + y*GRID_N + x];
    int gi = (c << 16) | idx;
    float rr = sr[gi], ii = si[gi];
    ax += rr*v.x + ii*v.y;      // conj(s)*v real
    ay += rr*v.y - ii*v.x;      // conj(s)*v imag
  }
  if (pairs){
    out[idx*2]   += ax * s2;
    out[idx*2+1] += ay * s2;
  } else {
    out[idx]     += ax * s2;
  }
}

// ---------------- fallback (round-2 validated fused atomic path) -------------
__global__ void k_zero4(float4* p, int n4){
  int i = blockIdx.x*blockDim.x + threadIdx.x;
  if (i < n4) p[i] = make_float4(0.f,0.f,0.f,0.f);
}

__global__ void k_fill_fb(const float* __restrict__ ximg, const float* __restrict__ sr,
                          const float* __restrict__ si, const float* __restrict__ sc,
                          cplx* __restrict__ A){
  int idx = blockIdx.x*blockDim.x + threadIdx.x;
  if (idx >= NCOIL*IM_N*IM_N) return;
  int c = idx >> 16;
  int pix = idx & 65535;
  int y = pix >> 8, x = pix & 255;
  float v = ximg[pix] * sc[y]*sc[x];
  cplx o; o.x = v * sr[idx]; o.y = v * si[idx];
  A[(size_t)c*PLANE + y*GRID_N + x] = o;
}

__global__ void k_gather_scatter_fb(const float* __restrict__ ktraj,
                                    const float* __restrict__ yre,
                                    const float* __restrict__ yim,
                                    const float* __restrict__ lraw,
                                    const cplx* __restrict__ KT,
                                    float* __restrict__ HT){
  int k = blockIdx.x*blockDim.x + threadIdx.x;
  if (k >= NK) return;
  float lam   = 1.0f/(1.0f + __expf(-lraw[0]));
  float omlam = 1.0f - lam;
  int iy[JW], ix[JW]; float wy[JW], wx[JW];
  {
    float tm = ktraj[k] * KSCALE;
    int base = (int)floorf(tm - 3.0f);
    #pragma unroll
    for (int j = 1; j <= JW; ++j){
      wy[j-1] = kb_w(tm - (float)(base+j));
      iy[j-1] = (base+j) & (GRID_N-1);
    }
  }
  {
    float tm = ktraj[NK + k] * KSCALE;
    int base = (int)floorf(tm - 3.0f);
    #pragma unroll
    for (int j = 1; j <= JW; ++j){
      wx[j-1] = kb_w(tm - (float)(base+j));
      ix[j-1] = (base+j) & (GRID_N-1);
    }
  }
  float accx[NCOIL], accy[NCOIL];
  #pragma unroll
  for (int c = 0; c < NCOIL; ++c){ accx[c]=0.f; accy[c]=0.f; }
  #pragma unroll
  for (int jx = 0; jx < JW; ++jx){
    int ox = ix[jx]*GRID_N;
    #pragma unroll
    for (int jy = 0; jy < JW; ++jy){
      float w2 = wx[jx]*wy[jy];
      size_t o = (size_t)(ox + iy[jy]);
      #pragma unroll
      for (int c = 0; c < NCOIL; ++c){
        cplx v = KT[(size_t)c*PLANE + o];
        accx[c] += w2*v.x; accy[c] += w2*v.y;
      }
    }
  }
  float kdx[NCOIL], kdy[NCOIL];
  #pragma unroll
  for (int c = 0; c < NCOIL; ++c){
    kdx[c] = lam*accx[c] + omlam*yre[(size_t)c*NK + k];
    kdy[c] = lam*accy[c] + omlam*yim[(size_t)c*NK + k];
  }
  #pragma unroll
  for (int jx = 0; jx < JW; ++jx){
    int ox = ix[jx]*GRID_N;
    #pragma unroll
    for (int jy = 0; jy < JW; ++jy){
      float w2 = wx[jx]*wy[jy];
      size_t o = (size_t)(ox + iy[jy]);
      #pragma unroll
      for (int c = 0; c < NCOIL; ++c){
        float* dst = HT + ((size_t)c*PLANE + o)*2;
        atomicAdd(dst,   w2*kdx[c]);
        atomicAdd(dst+1, w2*kdy[c]);
      }
    }
  }
}

extern "C" void kernel_launch(void* const* d_in, const int* in_sizes, int n_in,
                              void* d_out, int out_size, void* d_ws, size_t ws_size,
                              hipStream_t stream) {
  const float* ximg  = (const float*)d_in[0];
  const float* yre   = (const float*)d_in[1];
  const float* yim   = (const float*)d_in[2];
  const float* sre   = (const float*)d_in[3];
  const float* sim   = (const float*)d_in[4];
  const float* ktraj = (const float*)d_in[5];
  const float* lraw  = (const float*)d_in[6];
  float* out = (float*)d_out;

  char* ws = (char*)d_ws;
  const size_t REG = 16777216;                 // one planar grid: 512*512*8B*8
  int pairs = (out_size >= 2*IM_N*IM_N) ? 1 : 0;

  // primary layout (50.34 MB):
  //  R0 [0,REG): A planar (fwd fft) -> { kdc 8MB | hist2 1MB | cnt2 1MB |
  //              binOff 1MB+4 | colTot | colBase } -> imgF planar
  //  R1 [REG,2REG): Bb planar -> recs (786432 x 16B = 12.6MB)
  //  R2 [2REG,3REG): KTi interleaved -> Hp planar (k_adj out, ifft in-place)
  //  [3REG,...): sc (4KB)
  const size_t need = 3*REG + 4096;

  if (ws_size >= need){
    cplx*     A     = (cplx*)ws;                           // R0
    cplx*     Bb    = (cplx*)(ws + REG);                   // R1
    float4*   KTi4  = (float4*)(ws + 2*REG);               // R2
    float*    sc    = (float*)(ws + 3*REG);
    float4*   kdc4  = (float4*)ws;                         // R0 +0   (8MB)
    unsigned* hist2 = (unsigned*)(ws + 8388608);           // R0 +8M  (1MB)
    unsigned* cnt2  = (unsigned*)(ws + 9437184);           // R0 +9M  (1MB)
    unsigned* binOff= (unsigned*)(ws + 10485760);          // R0 +10M (1MB+4)
    unsigned* colTot= (unsigned*)(ws + 11538432);          // 2KB
    unsigned* colBase=(unsigned*)(ws + 11540480);          // 2052B
    uint4*    recs  = (uint4*)(ws + REG);                  // R1 (12.6MB)
    cplx*     Hp    = (cplx*)(ws + 2*REG);                 // R2 (over dead KTi)
    cplx*     imgF  = (cplx*)ws;                           // R0 (after k_adj)

    k_sc_table<<<1,256,0,stream>>>(sc);

    // fused pad+apodize+smap + fwd fft rows over x -> A planar [c][y][x]
    k_fft_fill<<<NCOIL*GRID_N,256,0,stream>>>(ximg, sre, sim, sc, A);
    k_transpose<<<dim3(16,16,NCOIL),dim3(32,8),0,stream>>>(A, Bb);
    k_fft_rows<-1><<<NCOIL*GRID_N,256,0,stream>>>(Bb, 1.0f/(float)GRID_N);

    k_c2i<<<(PLANE*NCOIL+255)/256,256,0,stream>>>((const float2*)Bb, (float2*)KTi4);

    // forward interp + blend -> kdc (overlays dead A region)
    k_fwd<<<(NK*4+255)/256,256,0,stream>>>(ktraj, yre, yim, lraw, KTi4, kdc4);

    // (col, by) binning: 2D histogram + hierarchical scan + placement
    k_zero1<<<(2*NBIN+255)/256,256,0,stream>>>((float*)hist2, 2*NBIN); // hist2+cnt2
    k_hist2<<<NK/256,256,0,stream>>>(ktraj, hist2);
    k_colscan<<<GRID_N,GRID_N,0,stream>>>(hist2, binOff, colTot);
    k_scanCT<<<1,GRID_N,0,stream>>>(colTot, colBase);
    k_addbase<<<(NBIN+256)/256,256,0,stream>>>(binOff, colBase);
    k_place<<<NK/256,256,0,stream>>>(ktraj, binOff, cnt2, recs);

    // adjoint gridding: r17 cooperative windows (2 q-half blocks/column),
    // single barrier/window, planar writeback to Hp
    k_adj<<<dim3(GRID_N,2),512,0,stream>>>(recs, binOff, (const float*)kdc4, Hp);

    // adjoint ifft2*512: rows over y (Hp in-place), crop-aware transpose
    // (only y_img<256 output rows), ifft over x on 256 rows/coil, x<256 write
    k_fft_rows<+1><<<NCOIL*GRID_N,256,0,stream>>>(Hp, 1.0f);
    k_transpose<<<dim3(8,16,NCOIL),dim3(32,8),0,stream>>>(Hp, imgF);
    k_fft_rows_c<<<NCOIL*IM_N,256,0,stream>>>(imgF, 1.0f/(float)GRID_N);

    k_zero1<<<(out_size+255)/256,256,0,stream>>>(out, out_size);
    k_final<<<(IM_N*IM_N+255)/256,256,0,stream>>>(imgF, sre, sim, sc, out, pairs);
  } else {
    // fallback: round-2 validated path (needs 33.6 MB)
    float* sc = (float*)ws;
    cplx*  A  = (cplx*)(ws + 4096);
    cplx*  Bb = (cplx*)(ws + 4096 + REG);
    const int n4 = NCOIL*PLANE*2/4;

    k_sc_table<<<1,256,0,stream>>>(sc);
    k_zero4<<<(n4+255)/256,256,0,stream>>>((float4*)A, n4);
    k_fill_fb<<<(NCOIL*IM_N*IM_N+255)/256,256,0,stream>>>(ximg, sre, sim, sc, A);
    k_fft_rows<-1><<<NCOIL*GRID_N,256,0,stream>>>(A, 1.0f);
    k_transpose<<<dim3(16,16,NCOIL),dim3(32,8),0,stream>>>(A, Bb);
    k_fft_rows<-1><<<NCOIL*GRID_N,256,0,stream>>>(Bb, 1.0f/(float)GRID_N);
    k_zero4<<<(n4+255)/256,256,0,stream>>>((float4*)A, n4);
    k_gather_scatter_fb<<<(NK+255)/256,256,0,stream>>>(ktraj, yre, yim, lraw, Bb, (float*)A);
    k_fft_rows<+1><<<NCOIL*GRID_N,256,0,stream>>>(A, 1.0f);
    k_transpose<<<dim3(16,16,NCOIL),dim3(32,8),0,stream>>>(A, Bb);
    k_fft_rows<+1><<<NCOIL*GRID_N,256,0,stream>>>(Bb, 1.0f/(float)GRID_N);
    k_zero1<<<(out_size+255)/256,256,0,stream>>>(out, out_size);
    k_final<<<(IM_N*IM_N+255)/256,256,0,stream>>>(Bb, sre, sim, sc, out, pairs);
  }
}

// Round 20
// 335.339 us; speedup vs baseline: 1.1867x; 1.1451x over previous
//
#include <hip/hip_runtime.h>
#include <math.h>

#define GRID_N 512
#define IM_N   256
#define NCOIL  8
#define NK     131072
#define PLANE  (GRID_N*GRID_N)
#define JW     6
#define NBIN   (GRID_N*GRID_N/512*512)  /* 262144 (col,by) bins */
#define WSZ    11
#define NWIN   47                        /* ceil(512/11) */
#define SPLITW 24                        /* windows owned by h=0 */
#define BASE1  (SPLITW*WSZ)              /* 264: h=1 base row */
#define NLROWS 272                       /* local accumulator rows */
#define BETA_F 13.8551003f   /* pi*sqrt((6/2)^2*(2-0.5)^2 - 0.8) */
#define KSCALE 81.48733086305042f  /* 512/(2*pi) */

struct cplx { float x, y; };

__device__ __forceinline__ float bessel_i0f(float x){
  // Abramowitz & Stegun 9.8.1 / 9.8.2, rel err < 2e-7
  if (x < 3.75f){
    float t = x*(1.0f/3.75f); t = t*t;
    return 1.0f + t*(3.5156229f + t*(3.0899424f + t*(1.2067492f
           + t*(0.2659732f + t*(0.0360768f + t*0.0045813f)))));
  } else {
    float t = 3.75f/x;
    float p = 0.39894228f + t*(0.01328592f + t*(0.00225319f + t*(-0.00157565f
            + t*(0.00916281f + t*(-0.02057706f + t*(0.02635537f
            + t*(-0.01647633f + t*0.00392377f)))))));
    return p * __expf(x) * rsqrtf(x);
  }
}

__device__ __forceinline__ float kb_w(float u){   // 1-axis KB weight, |u|<=3
  float uu = u*(1.0f/3.0f);
  float q = fmaxf(1.0f - uu*uu, 0.0f);
  return bessel_i0f(BETA_F*sqrtf(q)) * (1.0f/6.0f);
}

__device__ __forceinline__ unsigned bf16_of(float f){
  unsigned u = __float_as_uint(f);
  return (u + 0x8000u) >> 16;
}
__device__ __forceinline__ float bf_lo(unsigned w){ return __uint_as_float(w << 16); }
__device__ __forceinline__ float bf_hi(unsigned w){ return __uint_as_float(w & 0xFFFF0000u); }

// Kaiser-Bessel apodization correction row table sc[256]
__global__ void k_sc_table(float* sc){
  int i = threadIdx.x;
  if (i >= IM_N) return;
  float n  = (i - IM_N*0.5f) * (1.0f/GRID_N);
  float pj = 3.14159265358979f * (float)JW * n;
  float t  = BETA_F*BETA_F - pj*pj;
  float sp = sqrtf(fmaxf(t, 1e-12f));
  float sn = sqrtf(fmaxf(-t, 1e-12f));
  float ft = (t > 0.0f) ? (sinhf(sp)/sp) : (sinf(sn)/sn);
  float sc0 = sinhf(BETA_F)/BETA_F;
  sc[i] = sc0/ft;
}

__global__ void k_zero1(float* p, int n){
  int i = blockIdx.x*blockDim.x + threadIdx.x;
  if (i < n) p[i] = 0.f;
}

// FUSED: pad + apodize + smap-multiply + fwd 512-pt FFT row (DIR=-1, scale 1)
// block = c*512+y; rows y>=256 are identically zero -> direct zero store.
__global__ void k_fft_fill(const float* __restrict__ ximg, const float* __restrict__ sr,
                           const float* __restrict__ si, const float* __restrict__ sc,
                           cplx* __restrict__ buf){
  __shared__ cplx lds[GRID_N];
  int blk = blockIdx.x;                        // c*512 + y
  int c = blk >> 9, y = blk & (GRID_N-1);
  cplx* p = buf + (size_t)blk * GRID_N;
  int tid = threadIdx.x;
  if (y >= IM_N){
    cplx z; z.x = 0.f; z.y = 0.f;
    for (int i = tid; i < GRID_N; i += 256) p[i] = z;
    return;
  }
  float scy = sc[y];
  for (int i = tid; i < GRID_N; i += 256){
    int r = __brev((unsigned)i) >> 23;
    cplx v; v.x = 0.f; v.y = 0.f;
    if (i < IM_N){
      float vv = ximg[(y<<8)|i] * scy * sc[i];
      int gi = (c << 16) | (y << 8) | i;
      v.x = vv * sr[gi]; v.y = vv * si[gi];
    }
    lds[r] = v;
  }
  __syncthreads();
  for (int half = 1; half < GRID_N; half <<= 1){
    int j = tid & (half-1);
    int k = ((tid & ~(half-1)) << 1) | j;
    float ang = -3.14159265358979f * (float)j / (float)half;
    float sw, cw; __sincosf(ang, &sw, &cw);
    cplx u = lds[k];
    cplx v = lds[k+half];
    cplx t; t.x = v.x*cw - v.y*sw; t.y = v.x*sw + v.y*cw;
    lds[k].x      = u.x + t.x; lds[k].y      = u.y + t.y;
    lds[k+half].x = u.x - t.x; lds[k+half].y = u.y - t.y;
    __syncthreads();
  }
  for (int i = tid; i < GRID_N; i += 256) p[i] = lds[i];
}

// in-place 512-pt radix-2 FFT on each contiguous row; DIR=-1 fwd, +1 inv(unnorm)
template<int DIR>
__global__ void k_fft_rows(cplx* __restrict__ buf, float scale){
  __shared__ cplx lds[GRID_N];
  cplx* p = buf + (size_t)blockIdx.x * GRID_N;
  int tid = threadIdx.x;                       // 256 threads
  for (int i = tid; i < GRID_N; i += 256){
    int r = __brev((unsigned)i) >> 23;         // 9-bit reverse
    lds[r] = p[i];
  }
  __syncthreads();
  for (int half = 1; half < GRID_N; half <<= 1){
    int j = tid & (half-1);
    int k = ((tid & ~(half-1)) << 1) | j;
    float ang = (float)DIR * 3.14159265358979f * (float)j / (float)half;
    float sw, cw; __sincosf(ang, &sw, &cw);
    cplx u = lds[k];
    cplx v = lds[k+half];
    cplx t; t.x = v.x*cw - v.y*sw; t.y = v.x*sw + v.y*cw;
    lds[k].x      = u.x + t.x; lds[k].y      = u.y + t.y;
    lds[k+half].x = u.x - t.x; lds[k+half].y = u.y - t.y;
    __syncthreads();
  }
  for (int i = tid; i < GRID_N; i += 256){
    cplx v = lds[i]; v.x *= scale; v.y *= scale; p[i] = v;
  }
}

// ifft over y with SIDE-BUFFER MERGE (boundary rows from k_adj h=1 block).
// blockIdx.x = c*512 + col; merges side rows {1..15}->sidx 0..14,
// {265..269}->sidx 15..19 during the load phase. DIR=+1, scale=1.
__global__ void k_fft_rows_m(cplx* __restrict__ buf,
                             const float* __restrict__ side){
  __shared__ cplx lds[GRID_N];
  int blk = blockIdx.x;
  int c = blk >> 9, col = blk & (GRID_N-1);
  cplx* p = buf + (size_t)blk * GRID_N;
  int tid = threadIdx.x;
  for (int i = tid; i < GRID_N; i += 256){
    int r = __brev((unsigned)i) >> 23;
    cplx v = p[i];
    int sidx = -1;
    if (i >= 1 && i <= 15) sidx = i - 1;
    else if (i >= 265 && i <= 269) sidx = i - 250;
    if (sidx >= 0){
      const float* sp = side + ((size_t)col*20 + sidx)*16 + 2*c;
      v.x += sp[0]; v.y += sp[1];
    }
    lds[r] = v;
  }
  __syncthreads();
  for (int half = 1; half < GRID_N; half <<= 1){
    int j = tid & (half-1);
    int k = ((tid & ~(half-1)) << 1) | j;
    float ang = 3.14159265358979f * (float)j / (float)half;
    float sw, cw; __sincosf(ang, &sw, &cw);
    cplx u = lds[k];
    cplx v = lds[k+half];
    cplx t; t.x = v.x*cw - v.y*sw; t.y = v.x*sw + v.y*cw;
    lds[k].x      = u.x + t.x; lds[k].y      = u.y + t.y;
    lds[k+half].x = u.x - t.x; lds[k+half].y = u.y - t.y;
    __syncthreads();
  }
  for (int i = tid; i < GRID_N; i += 256) p[i] = lds[i];
}

// crop variant: 256 rows per coil (y<256), inverse FFT over x, write x<256 only
__global__ void k_fft_rows_c(cplx* __restrict__ buf, float scale){
  __shared__ cplx lds[GRID_N];
  int b = blockIdx.x;                          // c*256 + y
  int c = b >> 8, y = b & (IM_N-1);
  cplx* p = buf + (size_t)c*PLANE + (size_t)y*GRID_N;
  int tid = threadIdx.x;
  for (int i = tid; i < GRID_N; i += 256){
    int r = __brev((unsigned)i) >> 23;
    lds[r] = p[i];
  }
  __syncthreads();
  for (int half = 1; half < GRID_N; half <<= 1){
    int j = tid & (half-1);
    int k = ((tid & ~(half-1)) << 1) | j;
    float ang = 3.14159265358979f * (float)j / (float)half;
    float sw, cw; __sincosf(ang, &sw, &cw);
    cplx u = lds[k];
    cplx v = lds[k+half];
    cplx t; t.x = v.x*cw - v.y*sw; t.y = v.x*sw + v.y*cw;
    lds[k].x      = u.x + t.x; lds[k].y      = u.y + t.y;
    lds[k+half].x = u.x - t.x; lds[k+half].y = u.y - t.y;
    __syncthreads();
  }
  for (int i = tid; i < IM_N; i += 256){       // crop: only x<256 consumed
    cplx v = lds[i]; v.x *= scale; v.y *= scale; p[i] = v;
  }
}

// 512x512 (or partial) tile transpose per coil plane, out[X][Y] = in[Y][X]
__global__ void k_transpose(const cplx* __restrict__ in, cplx* __restrict__ out){
  __shared__ cplx tile[32][33];
  int c  = blockIdx.z;
  int x0 = blockIdx.x*32, y0 = blockIdx.y*32;
  const cplx* ip = in  + (size_t)c*PLANE;
  cplx*       op = out + (size_t)c*PLANE;
  int tx = threadIdx.x, ty = threadIdx.y;      // (32,8)
  for (int dy = 0; dy < 32; dy += 8)
    tile[ty+dy][tx] = ip[(size_t)(y0+ty+dy)*GRID_N + (x0+tx)];
  __syncthreads();
  for (int dy = 0; dy < 32; dy += 8)
    op[(size_t)(x0+ty+dy)*GRID_N + (y0+tx)] = tile[tx][ty+dy];
}

// planar [c][cell] -> coil-interleaved [cell][8 float2]  (fully coalesced)
__global__ void k_c2i(const float2* __restrict__ plan, float2* __restrict__ inter){
  int t = blockIdx.x*blockDim.x + threadIdx.x;
  if (t >= PLANE*NCOIL) return;
  int c = t & 7; int cell = t >> 3;
  inter[(size_t)cell*8 + c] = plan[(size_t)c*PLANE + cell];
}

// forward interp + lambda blend: thread = (sample, coil-pair)
__global__ __launch_bounds__(256) void k_fwd(
    const float* __restrict__ ktraj, const float* __restrict__ yre,
    const float* __restrict__ yim, const float* __restrict__ lraw,
    const float4* __restrict__ KTi4, float4* __restrict__ kdc4){
  int t = blockIdx.x*blockDim.x + threadIdx.x;
  if (t >= NK*4) return;
  int k = t >> 2, p = t & 3;

  int iy[JW], ix[JW]; float wy[JW], wx[JW];
  {
    float tm = ktraj[k] * KSCALE;
    int base = (int)floorf(tm - 3.0f);
    #pragma unroll
    for (int j = 1; j <= JW; ++j){
      int fidx = base + j;
      wy[j-1] = kb_w(tm - (float)fidx);
      iy[j-1] = fidx & (GRID_N-1);
    }
  }
  {
    float tm = ktraj[NK + k] * KSCALE;
    int base = (int)floorf(tm - 3.0f);
    #pragma unroll
    for (int j = 1; j <= JW; ++j){
      int fidx = base + j;
      wx[j-1] = kb_w(tm - (float)fidx);
      ix[j-1] = fidx & (GRID_N-1);
    }
  }

  float ax=0.f, ay=0.f, az=0.f, aw=0.f;
  #pragma unroll
  for (int jx = 0; jx < JW; ++jx){
    int ox = ix[jx]*GRID_N;
    #pragma unroll
    for (int jy = 0; jy < JW; ++jy){
      float w2 = wx[jx]*wy[jy];
      float4 v = KTi4[(size_t)(ox + iy[jy])*4 + p];
      ax += w2*v.x; ay += w2*v.y; az += w2*v.z; aw += w2*v.w;
    }
  }
  float lam = 1.0f/(1.0f + __expf(-lraw[0]));
  float oml = 1.0f - lam;
  int c0 = 2*p;
  float4 o;
  o.x = lam*ax + oml*yre[(size_t)c0*NK + k];
  o.y = lam*ay + oml*yim[(size_t)c0*NK + k];
  o.z = lam*az + oml*yre[(size_t)(c0+1)*NK + k];
  o.w = lam*aw + oml*yim[(size_t)(c0+1)*NK + k];
  kdc4[(size_t)k*4 + p] = o;
}

// 2D histogram over (column, y-base-class) bins
__global__ void k_hist2(const float* __restrict__ ktraj, unsigned* __restrict__ hist2){
  int k = blockIdx.x*blockDim.x + threadIdx.x;
  if (k >= NK) return;
  float tmy = ktraj[k] * KSCALE;
  int by = ((int)floorf(tmy - 3.0f)) & (GRID_N-1);
  float tmx = ktraj[NK + k] * KSCALE;
  int bx = (int)floorf(tmx - 3.0f);
  #pragma unroll
  for (int j = 1; j <= JW; ++j){
    int cj = (bx + j) & (GRID_N-1);
    atomicAdd(&hist2[cj*GRID_N + by], 1u);
  }
}

// per-column exclusive scan of 512 by-class counts; emits column totals
__global__ void k_colscan(const unsigned* __restrict__ hist2,
                          unsigned* __restrict__ binOff,
                          unsigned* __restrict__ colTotal){
  __shared__ unsigned s[GRID_N];
  int col = blockIdx.x, t = threadIdx.x;
  unsigned mine = hist2[col*GRID_N + t];
  s[t] = mine;
  __syncthreads();
  for (int off = 1; off < GRID_N; off <<= 1){
    unsigned add = (t >= off) ? s[t - off] : 0u;
    __syncthreads();
    s[t] += add;
    __syncthreads();
  }
  binOff[col*GRID_N + t] = s[t] - mine;        // exclusive within column
  if (t == GRID_N-1) colTotal[col] = s[t];
}

// scan 512 column totals -> column bases (+ grand total at [512])
__global__ void k_scanCT(const unsigned* __restrict__ colTotal,
                         unsigned* __restrict__ colBase){
  __shared__ unsigned s[GRID_N];
  int t = threadIdx.x;
  unsigned mine = colTotal[t];
  s[t] = mine;
  __syncthreads();
  for (int off = 1; off < GRID_N; off <<= 1){
    unsigned add = (t >= off) ? s[t - off] : 0u;
    __syncthreads();
    s[t] += add;
    __syncthreads();
  }
  colBase[t] = s[t] - mine;
  if (t == GRID_N-1) colBase[GRID_N] = s[t];
}

// binOff[i] += colBase[col]; sentinel at NBIN = grand total
__global__ void k_addbase(unsigned* __restrict__ binOff,
                          const unsigned* __restrict__ colBase){
  int i = blockIdx.x*blockDim.x + threadIdx.x;
  if (i > NBIN) return;
  if (i == NBIN){ binOff[i] = colBase[GRID_N]; return; }
  binOff[i] += colBase[i >> 9];
}

// place 16B records binned by (column, by):
// rec = { bf16(wx*wy1)|bf16(wx*wy2)<<16, .., (kk<<9)|by }
__global__ void k_place(const float* __restrict__ ktraj,
                        const unsigned* __restrict__ binOff,
                        unsigned* __restrict__ cnt2,
                        uint4* __restrict__ recs){
  int k = blockIdx.x*blockDim.x + threadIdx.x;
  if (k >= NK) return;
  float tmy = ktraj[k] * KSCALE;
  int by0 = (int)floorf(tmy - 3.0f);
  int by = by0 & (GRID_N-1);
  float wy[JW];
  #pragma unroll
  for (int j = 1; j <= JW; ++j) wy[j-1] = kb_w(tmy - (float)(by0 + j));

  float tmx = ktraj[NK + k] * KSCALE;
  int bx = (int)floorf(tmx - 3.0f);
  unsigned tag = ((unsigned)k << 9) | (unsigned)by;
  #pragma unroll
  for (int j = 1; j <= JW; ++j){
    int cj = (bx + j) & (GRID_N-1);
    float wx = kb_w(tmx - (float)(bx + j));
    uint4 rec;
    rec.x = bf16_of(wx*wy[0]) | (bf16_of(wx*wy[1]) << 16);
    rec.y = bf16_of(wx*wy[2]) | (bf16_of(wx*wy[3]) << 16);
    rec.z = bf16_of(wx*wy[4]) | (bf16_of(wx*wy[5]) << 16);
    rec.w = tag;
    int bin = cj*GRID_N + by;
    unsigned pos = binOff[bin] + atomicAdd(&cnt2[bin], 1u);
    recs[pos] = rec;
  }
}

// adjoint gridding, WINDOW-SPLIT cooperative kernel (r20).
// block = (column, h); h=0 owns windows [0,24) (rows 1..269),
// h=1 owns [24,47) (rows 265..527 incl wrap). Each record visited ONCE
// (lane = slot 0..3 x q 0..15 covers all 16 coil-floats). Per-window:
// tree (r17-validated) -> 2-level shfl slot-reduce -> part -> fold into
// 272-row local accumulator (17KB + 8KB part = 25.6KB, occupancy kept).
// Boundary rows (1..15 wrap, 265..269 overlap) from h=1 go to SIDE buffer,
// merged in k_fft_rows_m; all other rows plain-stored by their sole owner.
__global__ __launch_bounds__(512) void k_adj(
    const uint4* __restrict__ recs, const unsigned* __restrict__ binOff,
    const float* __restrict__ kdcf, cplx* __restrict__ Hp,
    float* __restrict__ side){
  __shared__ float accs[NLROWS*16];            // 17 KB
  __shared__ float part[8][16][16];            // 8 KB
  const int col = blockIdx.x, h = blockIdx.y;
  const int tid = threadIdx.x;
  const int wave = tid >> 6, lane = tid & 63;
  const int slot = lane >> 4, q = lane & 15;
  for (int i = tid; i < NLROWS*16; i += 512) accs[i] = 0.f;
  __syncthreads();

  const unsigned* bo = binOff + (size_t)col*GRID_N;
  const int wlo = h ? SPLITW : 0;
  const int whi = h ? NWIN : SPLITW;
  const int base0 = h ? BASE1 : 0;

  for (int wi = wlo; wi < whi; ++wi){
    int b0 = wi*WSZ;
    int b1 = b0 + WSZ; if (b1 > GRID_N) b1 = GRID_N;
    unsigned s = bo[b0];
    unsigned e = bo[b1];
    if (s == e) continue;                      // uniform across block

    float a0=0.f,a1=0.f,a2=0.f,a3=0.f,a4=0.f,a5=0.f,a6=0.f,a7=0.f;
    float a8=0.f,a9=0.f,a10=0.f,a11=0.f,a12=0.f,a13=0.f,a14=0.f,a15=0.f;

    for (unsigned base = s + (unsigned)wave*4; base < e; base += 32){
      unsigned e0 = base + (unsigned)slot;
      uint4 rc = recs[e0];                     // may over-read; guarded below
      float vv = 0.f;
      if (e0 < e){
        unsigned kk = (rc.w >> 9) & (NK-1);
        vv = kdcf[(size_t)kk*16 + q];
      }
      float w1 = bf_lo(rc.x), w2 = bf_hi(rc.x);
      float w3 = bf_lo(rc.y), w4 = bf_hi(rc.y);
      float w5 = bf_lo(rc.z), w6 = bf_hi(rc.z);
      int off = (int)(rc.w & (GRID_N-1)) - b0; // 0..10
      #pragma unroll
      for (int r = 0; r < 16; ++r){
        int idx = r - off;                     // tap index 0..5 = w_{idx+1}
        float wlo2 = (idx < 2) ? w1 : ((idx < 4) ? w3 : w5);
        float whi2 = (idx < 2) ? w2 : ((idx < 4) ? w4 : w6);
        float w = (idx & 1) ? whi2 : wlo2;
        w = ((unsigned)idx < 6u) ? w : 0.f;
        float contrib = w * vv;
        if (r==0) a0+=contrib; else if (r==1) a1+=contrib;
        else if (r==2) a2+=contrib; else if (r==3) a3+=contrib;
        else if (r==4) a4+=contrib; else if (r==5) a5+=contrib;
        else if (r==6) a6+=contrib; else if (r==7) a7+=contrib;
        else if (r==8) a8+=contrib; else if (r==9) a9+=contrib;
        else if (r==10) a10+=contrib; else if (r==11) a11+=contrib;
        else if (r==12) a12+=contrib; else if (r==13) a13+=contrib;
        else if (r==14) a14+=contrib; else a15+=contrib;
      }
    }

    // slot-reduce: slot = lane bits 4..5 -> xor masks 16, 32
    #pragma unroll
    for (int m = 16; m <= 32; m <<= 1){
      a0 += __shfl_xor(a0, m);  a1 += __shfl_xor(a1, m);
      a2 += __shfl_xor(a2, m);  a3 += __shfl_xor(a3, m);
      a4 += __shfl_xor(a4, m);  a5 += __shfl_xor(a5, m);
      a6 += __shfl_xor(a6, m);  a7 += __shfl_xor(a7, m);
      a8 += __shfl_xor(a8, m);  a9 += __shfl_xor(a9, m);
      a10 += __shfl_xor(a10, m); a11 += __shfl_xor(a11, m);
      a12 += __shfl_xor(a12, m); a13 += __shfl_xor(a13, m);
      a14 += __shfl_xor(a14, m); a15 += __shfl_xor(a15, m);
    }
    if (slot == 0){                            // lanes 0..15, q = lane
      part[wave][0][q]  = a0;  part[wave][1][q]  = a1;
      part[wave][2][q]  = a2;  part[wave][3][q]  = a3;
      part[wave][4][q]  = a4;  part[wave][5][q]  = a5;
      part[wave][6][q]  = a6;  part[wave][7][q]  = a7;
      part[wave][8][q]  = a8;  part[wave][9][q]  = a9;
      part[wave][10][q] = a10; part[wave][11][q] = a11;
      part[wave][12][q] = a12; part[wave][13][q] = a13;
      part[wave][14][q] = a14; part[wave][15][q] = a15;
    }
    __syncthreads();
    if (tid < 256){
      int r = tid >> 4, qq = tid & 15;
      float sum = part[0][r][qq] + part[1][r][qq] + part[2][r][qq]
                + part[3][r][qq] + part[4][r][qq] + part[5][r][qq]
                + part[6][r][qq] + part[7][r][qq];
      accs[(size_t)(b0 + 1 + r - base0)*16 + qq] += sum;
    }
    __syncthreads();
  }

  // writeback with ownership (no atomics):
  //  h=0: rows 1..269 plain.
  //  h=1: row 0 (wrap g=512) plain; rows 270..511 plain;
  //       wrap rows 1..15 -> side sidx 0..14; rows 265..269 -> side 15..19.
  for (int i = tid; i < NLROWS*8; i += 512){
    int l = i >> 3, j = i & 7;
    if (h == 0){
      if (l < 1 || l > 269) continue;
      cplx o; o.x = accs[l*16 + 2*j]; o.y = accs[l*16 + 2*j + 1];
      Hp[(size_t)j*PLANE + (size_t)col*GRID_N + l] = o;
    } else {
      if (l < 1 || l > 263) continue;          // g in 265..527
      int g = BASE1 + l;
      float re = accs[l*16 + 2*j], im = accs[l*16 + 2*j + 1];
      if (g >= 512){
        int gw = g - 512;                      // 0..15
        if (gw == 0){
          cplx o; o.x = re; o.y = im;
          Hp[(size_t)j*PLANE + (size_t)col*GRID_N] = o;
        } else {
          float* sp = side + ((size_t)col*20 + (gw-1))*16 + 2*j;
          sp[0] = re; sp[1] = im;
        }
      } else if (g >= 270){
        cplx o; o.x = re; o.y = im;
        Hp[(size_t)j*PLANE + (size_t)col*GRID_N + g] = o;
      } else {                                 // g 265..269 -> sidx 15..19
        float* sp = side + ((size_t)col*20 + (g-250))*16 + 2*j;
        sp[0] = re; sp[1] = im;
      }
    }
  }
}

// crop, apodize, conj(smaps) coil-combine; ACCUMULATES into out
__global__ void k_final(const cplx* __restrict__ Bg, const float* __restrict__ sr,
                        const float* __restrict__ si, const float* __restrict__ sc,
                        float* __restrict__ out, int pairs){
  int idx = blockIdx.x*blockDim.x + threadIdx.x;   // y*256+x
  if (idx >= IM_N*IM_N) return;
  int y = idx >> 8, x = idx & 255;
  float s2 = sc[y]*sc[x];
  float ax = 0.f, ay = 0.f;
  #pragma unroll
  for (int c = 0; c < NCOIL; ++c){
    cplx v = Bg[(size_t)c*PLANE + y*GRID_N + x];
    int gi = (c << 16) | idx;
    float rr = sr[gi], ii = si[gi];
    ax += rr*v.x + ii*v.y;      // conj(s)*v real
    ay += rr*v.y - ii*v.x;      // conj(s)*v imag
  }
  if (pairs){
    out[idx*2]   += ax * s2;
    out[idx*2+1] += ay * s2;
  } else {
    out[idx]     += ax * s2;
  }
}

// ---------------- fallback (round-2 validated fused atomic path) -------------
__global__ void k_zero4(float4* p, int n4){
  int i = blockIdx.x*blockDim.x + threadIdx.x;
  if (i < n4) p[i] = make_float4(0.f,0.f,0.f,0.f);
}

__global__ void k_fill_fb(const float* __restrict__ ximg, const float* __restrict__ sr,
                          const float* __restrict__ si, const float* __restrict__ sc,
                          cplx* __restrict__ A){
  int idx = blockIdx.x*blockDim.x + threadIdx.x;
  if (idx >= NCOIL*IM_N*IM_N) return;
  int c = idx >> 16;
  int pix = idx & 65535;
  int y = pix >> 8, x = pix & 255;
  float v = ximg[pix] * sc[y]*sc[x];
  cplx o; o.x = v * sr[idx]; o.y = v * si[idx];
  A[(size_t)c*PLANE + y*GRID_N + x] = o;
}

__global__ void k_gather_scatter_fb(const float* __restrict__ ktraj,
                                    const float* __restrict__ yre,
                                    const float* __restrict__ yim,
                                    const float* __restrict__ lraw,
                                    const cplx* __restrict__ KT,
                                    float* __restrict__ HT){
  int k = blockIdx.x*blockDim.x + threadIdx.x;
  if (k >= NK) return;
  float lam   = 1.0f/(1.0f + __expf(-lraw[0]));
  float omlam = 1.0f - lam;
  int iy[JW], ix[JW]; float wy[JW], wx[JW];
  {
    float tm = ktraj[k] * KSCALE;
    int base = (int)floorf(tm - 3.0f);
    #pragma unroll
    for (int j = 1; j <= JW; ++j){
      wy[j-1] = kb_w(tm - (float)(base+j));
      iy[j-1] = (base+j) & (GRID_N-1);
    }
  }
  {
    float tm = ktraj[NK + k] * KSCALE;
    int base = (int)floorf(tm - 3.0f);
    #pragma unroll
    for (int j = 1; j <= JW; ++j){
      wx[j-1] = kb_w(tm - (float)(base+j));
      ix[j-1] = (base+j) & (GRID_N-1);
    }
  }
  float accx[NCOIL], accy[NCOIL];
  #pragma unroll
  for (int c = 0; c < NCOIL; ++c){ accx[c]=0.f; accy[c]=0.f; }
  #pragma unroll
  for (int jx = 0; jx < JW; ++jx){
    int ox = ix[jx]*GRID_N;
    #pragma unroll
    for (int jy = 0; jy < JW; ++jy){
      float w2 = wx[jx]*wy[jy];
      size_t o = (size_t)(ox + iy[jy]);
      #pragma unroll
      for (int c = 0; c < NCOIL; ++c){
        cplx v = KT[(size_t)c*PLANE + o];
        accx[c] += w2*v.x; accy[c] += w2*v.y;
      }
    }
  }
  float kdx[NCOIL], kdy[NCOIL];
  #pragma unroll
  for (int c = 0; c < NCOIL; ++c){
    kdx[c] = lam*accx[c] + omlam*yre[(size_t)c*NK + k];
    kdy[c] = lam*accy[c] + omlam*yim[(size_t)c*NK + k];
  }
  #pragma unroll
  for (int jx = 0; jx < JW; ++jx){
    int ox = ix[jx]*GRID_N;
    #pragma unroll
    for (int jy = 0; jy < JW; ++jy){
      float w2 = wx[jx]*wy[jy];
      size_t o = (size_t)(ox + iy[jy]);
      #pragma unroll
      for (int c = 0; c < NCOIL; ++c){
        float* dst = HT + ((size_t)c*PLANE + o)*2;
        atomicAdd(dst,   w2*kdx[c]);
        atomicAdd(dst+1, w2*kdy[c]);
      }
    }
  }
}

extern "C" void kernel_launch(void* const* d_in, const int* in_sizes, int n_in,
                              void* d_out, int out_size, void* d_ws, size_t ws_size,
                              hipStream_t stream) {
  const float* ximg  = (const float*)d_in[0];
  const float* yre   = (const float*)d_in[1];
  const float* yim   = (const float*)d_in[2];
  const float* sre   = (const float*)d_in[3];
  const float* sim   = (const float*)d_in[4];
  const float* ktraj = (const float*)d_in[5];
  const float* lraw  = (const float*)d_in[6];
  float* out = (float*)d_out;

  char* ws = (char*)d_ws;
  const size_t REG = 16777216;                 // one planar grid: 512*512*8B*8
  int pairs = (out_size >= 2*IM_N*IM_N) ? 1 : 0;

  // primary layout (50.34 MB):
  //  R0 [0,REG): A planar (fwd fft) -> { kdc 8MB | hist2 1MB | cnt2 1MB |
  //              binOff 1MB+4 | colTot | colBase | side 655KB@12MB } -> imgF
  //  R1 [REG,2REG): Bb planar -> recs (786432 x 16B = 12.6MB)
  //  R2 [2REG,3REG): KTi interleaved -> Hp planar (k_adj out, ifft in-place)
  //  [3REG,...): sc (4KB)
  const size_t need = 3*REG + 4096;

  if (ws_size >= need){
    cplx*     A     = (cplx*)ws;                           // R0
    cplx*     Bb    = (cplx*)(ws + REG);                   // R1
    float4*   KTi4  = (float4*)(ws + 2*REG);               // R2
    float*    sc    = (float*)(ws + 3*REG);
    float4*   kdc4  = (float4*)ws;                         // R0 +0   (8MB)
    unsigned* hist2 = (unsigned*)(ws + 8388608);           // R0 +8M  (1MB)
    unsigned* cnt2  = (unsigned*)(ws + 9437184);           // R0 +9M  (1MB)
    unsigned* binOff= (unsigned*)(ws + 10485760);          // R0 +10M (1MB+4)
    unsigned* colTot= (unsigned*)(ws + 11538432);          // 2KB
    unsigned* colBase=(unsigned*)(ws + 11540480);          // 2052B
    float*    side  = (float*)(ws + 12582912);             // R0 +12M (655KB)
    uint4*    recs  = (uint4*)(ws + REG);                  // R1 (12.6MB)
    cplx*     Hp    = (cplx*)(ws + 2*REG);                 // R2 (over dead KTi)
    cplx*     imgF  = (cplx*)ws;                           // R0 (after ifft-y)

    k_sc_table<<<1,256,0,stream>>>(sc);

    // fused pad+apodize+smap + fwd fft rows over x -> A planar [c][y][x]
    k_fft_fill<<<NCOIL*GRID_N,256,0,stream>>>(ximg, sre, sim, sc, A);
    k_transpose<<<dim3(16,16,NCOIL),dim3(32,8),0,stream>>>(A, Bb);
    k_fft_rows<-1><<<NCOIL*GRID_N,256,0,stream>>>(Bb, 1.0f/(float)GRID_N);

    k_c2i<<<(PLANE*NCOIL+255)/256,256,0,stream>>>((const float2*)Bb, (float2*)KTi4);

    // forward interp + blend -> kdc (overlays dead A region)
    k_fwd<<<(NK*4+255)/256,256,0,stream>>>(ktraj, yre, yim, lraw, KTi4, kdc4);

    // (col, by) binning: 2D histogram + hierarchical scan + placement
    k_zero1<<<(2*NBIN+255)/256,256,0,stream>>>((float*)hist2, 2*NBIN); // hist2+cnt2
    k_hist2<<<NK/256,256,0,stream>>>(ktraj, hist2);
    k_colscan<<<GRID_N,GRID_N,0,stream>>>(hist2, binOff, colTot);
    k_scanCT<<<1,GRID_N,0,stream>>>(colTot, colBase);
    k_addbase<<<(NBIN+256)/256,256,0,stream>>>(binOff, colBase);
    k_place<<<NK/256,256,0,stream>>>(ktraj, binOff, cnt2, recs);

    // adjoint gridding: window-split cooperative blocks (records visited once),
    // planar writeback to Hp; boundary rows to side buffer
    k_adj<<<dim3(GRID_N,2),512,0,stream>>>(recs, binOff, (const float*)kdc4,
                                           Hp, side);

    // adjoint ifft2*512: ifft over y with side merge, crop-aware transpose,
    // ifft over x on 256 rows/coil, x<256 write
    k_fft_rows_m<<<NCOIL*GRID_N,256,0,stream>>>(Hp, side);
    k_transpose<<<dim3(8,16,NCOIL),dim3(32,8),0,stream>>>(Hp, imgF);
    k_fft_rows_c<<<NCOIL*IM_N,256,0,stream>>>(imgF, 1.0f/(float)GRID_N);

    k_zero1<<<(out_size+255)/256,256,0,stream>>>(out, out_size);
    k_final<<<(IM_N*IM_N+255)/256,256,0,stream>>>(imgF, sre, sim, sc, out, pairs);
  } else {
    // fallback: round-2 validated path (needs 33.6 MB)
    float* sc = (float*)ws;
    cplx*  A  = (cplx*)(ws + 4096);
    cplx*  Bb = (cplx*)(ws + 4096 + REG);
    const int n4 = NCOIL*PLANE*2/4;

    k_sc_table<<<1,256,0,stream>>>(sc);
    k_zero4<<<(n4+255)/256,256,0,stream>>>((float4*)A, n4);
    k_fill_fb<<<(NCOIL*IM_N*IM_N+255)/256,256,0,stream>>>(ximg, sre, sim, sc, A);
    k_fft_rows<-1><<<NCOIL*GRID_N,256,0,stream>>>(A, 1.0f);
    k_transpose<<<dim3(16,16,NCOIL),dim3(32,8),0,stream>>>(A, Bb);
    k_fft_rows<-1><<<NCOIL*GRID_N,256,0,stream>>>(Bb, 1.0f/(float)GRID_N);
    k_zero4<<<(n4+255)/256,256,0,stream>>>((float4*)A, n4);
    k_gather_scatter_fb<<<(NK+255)/256,256,0,stream>>>(ktraj, yre, yim, lraw, Bb, (float*)A);
    k_fft_rows<+1><<<NCOIL*GRID_N,256,0,stream>>>(A, 1.0f);
    k_transpose<<<dim3(16,16,NCOIL),dim3(32,8),0,stream>>>(A, Bb);
    k_fft_rows<+1><<<NCOIL*GRID_N,256,0,stream>>>(Bb, 1.0f/(float)GRID_N);
    k_zero1<<<(out_size+255)/256,256,0,stream>>>(out, out_size);
    k_final<<<(IM_N*IM_N+255)/256,256,0,stream>>>(Bb, sre, sim, sc, out, pairs);
  }
}